// Round 11
// baseline (356.193 us; speedup 1.0000x reference)
//
#include <hip/hip_runtime.h>
#include <stdint.h>

#define NN 20000
#define NE 200000   // == 3125 * 64 exactly (k_edge_all assumes this)
// H=128, NH=8, HD=16, RBF=64

typedef __attribute__((ext_vector_type(8))) short bf16x8;
typedef __attribute__((ext_vector_type(4))) float f32x4;

__device__ __forceinline__ float bf2f(uint32_t u) {
  union { uint32_t i; float f; } v; v.i = u << 16; return v.f;
}
__device__ __forceinline__ uint16_t f2bf(float f) {
  union { float f; uint32_t i; } v; v.f = f;
  return (uint16_t)((v.i + 0x7fffu + ((v.i >> 16) & 1u)) >> 16);
}
__device__ __forceinline__ uint32_t pk2(float lo, float hi) {
  return (uint32_t)f2bf(lo) | ((uint32_t)f2bf(hi) << 16);
}
__device__ __forceinline__ float siluf(float x) { return x / (1.f + __expf(-x)); }
__device__ __forceinline__ float prod2(uint32_t q2, uint32_t k2, uint32_t d2) {
  return bf2f(q2 & 0xffffu) * bf2f(k2 & 0xffffu) * bf2f(d2 & 0xffffu)
       + bf2f(q2 >> 16) * bf2f(k2 >> 16) * bf2f(d2 >> 16);
}

// ---------------- consolidated weight prep (one launch) ----------------
// WTqkv [768][128]: rows 0-255 = q|k; rows 256-767 v INTERLEAVED
// (row 256 + j*4 + c, j=h*16+d, c=0..2 from orig col h*48+c*16+d, c==3 pad).
// WTdkv2 [512][64] column-reordered: dk | xm | m1 | m2.
__global__ void k_prep(const float* __restrict__ Wq, const float* __restrict__ Wk,
                       const float* __restrict__ Wv, const float* __restrict__ Wvec,
                       const float* __restrict__ Wdk, const float* __restrict__ Wdv,
                       const float* __restrict__ Wo, const float* __restrict__ bq,
                       const float* __restrict__ bk, const float* __restrict__ bv,
                       const float* __restrict__ bdk, const float* __restrict__ bdv,
                       uint16_t* __restrict__ WTqkv, uint16_t* __restrict__ WTvec,
                       uint16_t* __restrict__ WTdkv2, uint16_t* __restrict__ WTo,
                       float* __restrict__ Bqkv, float* __restrict__ Bdkv2) {
  int idx = blockIdx.x * 256 + threadIdx.x;
  if (idx < 98304) {                       // WTqkv [768][128]
    int rr = idx >> 7, k = idx & 127;
    float v;
    if (rr < 128)      v = Wq[k * 128 + rr];
    else if (rr < 256) v = Wk[k * 128 + rr - 128];
    else {
      int j2 = rr - 256, j = j2 >> 2, c = j2 & 3;
      v = (c < 3) ? Wv[k * 384 + (j >> 4) * 48 + c * 16 + (j & 15)] : 0.f;
    }
    WTqkv[idx] = f2bf(v);
    return;
  }
  idx -= 98304;
  if (idx < 49152) {                       // WTvec [384][128]
    int c = idx >> 7, k = idx & 127;
    WTvec[idx] = f2bf(Wvec[k * 384 + c]);
    return;
  }
  idx -= 49152;
  if (idx < 32768) {                       // WTdkv2 [512][64], reordered
    int rr = idx >> 6, k = idx & 63;
    float v;
    if (rr < 128) v = Wdk[k * 128 + rr];
    else {
      int j = rr - 128, p = j >> 7, hd = j & 127;
      v = Wdv[k * 384 + (hd >> 4) * 48 + p * 16 + (hd & 15)];
    }
    WTdkv2[idx] = f2bf(v);
    return;
  }
  idx -= 32768;
  if (idx < 49152) {                       // WTo [384][128]
    int c = idx >> 7, k = idx & 127;
    WTo[idx] = f2bf(Wo[k * 384 + c]);
    return;
  }
  idx -= 49152;
  if (idx < 768) {                         // Bqkv [768]
    if (idx < 128)      Bqkv[idx] = bq[idx];
    else if (idx < 256) Bqkv[idx] = bk[idx - 128];
    else {
      int j2 = idx - 256, j = j2 >> 2, c = j2 & 3;
      Bqkv[idx] = (c < 3) ? bv[(j >> 4) * 48 + c * 16 + (j & 15)] : 0.f;
    }
  } else if (idx < 1280) {
    int t = idx - 768;
    if (t < 128) Bdkv2[t] = bdk[t];
    else {
      int j = t - 128, p = j >> 7, hd = j & 127;
      Bdkv2[t] = bdv[(hd >> 4) * 48 + p * 16 + (hd & 15)];
    }
  }
}

// ---------------- node pre: LN(x)->bf16 + vec walk-slots of combo (12B rows) ----------------
__global__ void k_node_pre(const float* __restrict__ x, const float* __restrict__ s,
                           const float* __restrict__ b, const float* __restrict__ vec,
                           uint16_t* __restrict__ xn_b, uint16_t* __restrict__ combo) {
  if (blockIdx.x < 5000) {
    int gt = blockIdx.x * 256 + threadIdx.x;
    int node = gt >> 6, lane = gt & 63;
    if (node >= NN) return;
    const float* row = x + (size_t)node * 128;
    float2 v = *(const float2*)&row[lane * 2];
    float sum = v.x + v.y, sq = v.x * v.x + v.y * v.y;
    #pragma unroll
    for (int off = 32; off; off >>= 1) { sum += __shfl_xor(sum, off); sq += __shfl_xor(sq, off); }
    float mu = sum * (1.f / 128.f);
    float var = sq * (1.f / 128.f) - mu * mu;
    float rs = rsqrtf(var + 1e-6f);
    float o0 = (v.x - mu) * rs * s[lane * 2] + b[lane * 2];
    float o1 = (v.y - mu) * rs * s[lane * 2 + 1] + b[lane * 2 + 1];
    ((uint32_t*)xn_b)[(size_t)node * 64 + lane] = pk2(o0, o1);
  } else {
    int i = (blockIdx.x - 5000) * 256 + threadIdx.x;  // NN*128 triples
    if (i >= NN * 128) return;
    int n = i >> 7, j = i & 127;
    const float* vr = vec + (size_t)n * 384 + j;
    uint16_t* cb = &combo[(size_t)n * 768 + j * 6];
    cb[3] = f2bf(vr[0]);                          // w0
    *(uint32_t*)&cb[4] = pk2(vr[128], vr[256]);   // w1|w2 (4B aligned)
  }
}

// ---------------- edge sort by receiver (counting sort, parallel scan) ----------------
__global__ void k_hist(const int* __restrict__ rcv, int* __restrict__ deg) {
  int e = blockIdx.x * 256 + threadIdx.x;
  if (e < NE) atomicAdd(&deg[rcv[e]], 1);
}

__global__ void k_scan1(const int* __restrict__ deg, int* __restrict__ bsum) {
  __shared__ int ws[4];
  int i = blockIdx.x * 256 + threadIdx.x;
  int x = (i < NN) ? deg[i] : 0;
  #pragma unroll
  for (int d = 32; d; d >>= 1) x += __shfl_xor(x, d);
  if ((threadIdx.x & 63) == 0) ws[threadIdx.x >> 6] = x;
  __syncthreads();
  if (threadIdx.x == 0) bsum[blockIdx.x] = ws[0] + ws[1] + ws[2] + ws[3];
}

__global__ void k_scan2(int* __restrict__ bsum, int nb, int* __restrict__ off) {
  int lane = threadIdx.x;
  int carry = 0;
  for (int base = 0; base < nb; base += 64) {
    int i = base + lane;
    int x = (i < nb) ? bsum[i] : 0;
    int v = x;
    #pragma unroll
    for (int d = 1; d < 64; d <<= 1) { int y = __shfl_up(v, d); if (lane >= d) v += y; }
    if (i < nb) bsum[i] = carry + v - x;
    carry += __shfl(v, 63);
  }
  if (lane == 0) off[NN] = carry;
}

__global__ void k_scan3(const int* __restrict__ deg, const int* __restrict__ bsum,
                        int* __restrict__ off, int* __restrict__ cur) {
  __shared__ int ws[4];
  int t = threadIdx.x, lane = t & 63, w = t >> 6;
  int i = blockIdx.x * 256 + t;
  int x = (i < NN) ? deg[i] : 0;
  int v = x;
  #pragma unroll
  for (int d = 1; d < 64; d <<= 1) { int y = __shfl_up(v, d); if (lane >= d) v += y; }
  if (lane == 63) ws[w] = v;
  __syncthreads();
  int wadd = 0;
  for (int j = 0; j < w; j++) wadd += ws[j];
  int excl = bsum[blockIdx.x] + wadd + v - x;
  if (i < NN) { off[i] = excl; cur[i] = excl; }
}

__global__ void k_scatter(const int* __restrict__ rcv, int* __restrict__ cur,
                          int* __restrict__ perm) {
  int e = blockIdx.x * 256 + threadIdx.x;
  if (e >= NE) return;
  int pos = atomicAdd(&cur[rcv[e]], 1);
  perm[pos] = e;
}

// gather+cast edge_attr rows in permuted order; also permute snd/rcv and
// pack (evec.xyz, cutoff(ew)) into edata
__global__ void k_permute(const float* __restrict__ ea, const int* __restrict__ perm,
                          const int* __restrict__ snd, const int* __restrict__ rcv,
                          const float* __restrict__ ew, const float* __restrict__ evec,
                          uint16_t* __restrict__ ea_perm, int* __restrict__ sndp,
                          int* __restrict__ rcvp, float4* __restrict__ edata) {
  int idx = blockIdx.x * 256 + threadIdx.x;   // 16 threads per edge
  if (idx >= NE * 16) return;
  int i = idx >> 4, j = idx & 15;
  int e = perm[i];
  float4 v = *(const float4*)&ea[(size_t)e * 64 + j * 4];
  uint2 o;
  o.x = pk2(v.x, v.y);
  o.y = pk2(v.z, v.w);
  *(uint2*)&ea_perm[(size_t)i * 64 + j * 4] = o;
  if (j == 0) {
    sndp[i] = snd[e];
    rcvp[i] = rcv[e];
    float w = ew[e];
    float cut = (w < 5.f) ? 0.5f * (__cosf(w * 0.628318530717958648f) + 1.f) : 0.f;
    edata[i] = make_float4(evec[e * 3], evec[e * 3 + 1], evec[e * 3 + 2], cut);
  }
}

// ---------------- bf16 MFMA GEMM: C = act(A @ BT^T + bias) ----------------
// AF32: A is f32, cast to bf16 during LDS staging.
template <int KTOT, bool OUT_BF16, bool SILU, bool AF32>
__global__ __launch_bounds__(256) void k_gemm(const void* __restrict__ A,
                                              const uint16_t* __restrict__ BT,
                                              const float* __restrict__ bias,
                                              void* __restrict__ Cout, int M, int Fo) {
  __shared__ __align__(16) uint16_t As[128 * 72];
  __shared__ __align__(16) uint16_t Bs[128 * 72];
  const uint16_t* A16 = (const uint16_t*)A;
  const float* A32 = (const float*)A;
  int t = threadIdx.x;
  int l = t & 63;
  int row0 = blockIdx.y * 128, col0 = blockIdx.x * 128;
  int wm = ((t >> 6) >> 1) * 64, wn = ((t >> 6) & 1) * 64;
  f32x4 acc[4][4] = {};
  for (int kt = 0; kt < KTOT; kt += 64) {
    __syncthreads();
    #pragma unroll
    for (int i = 0; i < 4; i++) {
      int c = i * 256 + t;
      int row = c >> 3, ko = (c & 7) * 8;
      uint4 av = make_uint4(0u, 0u, 0u, 0u);
      int gr = row0 + row;
      if (gr < M) {
        if (AF32) {
          float4 f0 = *(const float4*)&A32[(size_t)gr * KTOT + kt + ko];
          float4 f1 = *(const float4*)&A32[(size_t)gr * KTOT + kt + ko + 4];
          av = make_uint4(pk2(f0.x, f0.y), pk2(f0.z, f0.w), pk2(f1.x, f1.y), pk2(f1.z, f1.w));
        } else {
          av = *(const uint4*)&A16[(size_t)gr * KTOT + kt + ko];
        }
      }
      *(uint4*)&As[row * 72 + ko] = av;
      uint4 bw = *(const uint4*)&BT[(size_t)(col0 + row) * KTOT + kt + ko];
      *(uint4*)&Bs[row * 72 + ko] = bw;
    }
    __syncthreads();
    #pragma unroll
    for (int kk = 0; kk < 64; kk += 32) {
      bf16x8 af[4], bfr[4];
      #pragma unroll
      for (int mf = 0; mf < 4; mf++)
        af[mf] = *(const bf16x8*)&As[(wm + mf * 16 + (l & 15)) * 72 + (l >> 4) * 8 + kk];
      #pragma unroll
      for (int nf = 0; nf < 4; nf++)
        bfr[nf] = *(const bf16x8*)&Bs[(wn + nf * 16 + (l & 15)) * 72 + (l >> 4) * 8 + kk];
      #pragma unroll
      for (int mf = 0; mf < 4; mf++)
        #pragma unroll
        for (int nf = 0; nf < 4; nf++)
          acc[mf][nf] = __builtin_amdgcn_mfma_f32_16x16x32_bf16(af[mf], bfr[nf], acc[mf][nf], 0, 0, 0);
    }
  }
  float* Cf = (float*)Cout;
  uint16_t* Cb = (uint16_t*)Cout;
  #pragma unroll
  for (int mf = 0; mf < 4; mf++) {
    #pragma unroll
    for (int r = 0; r < 4; r++) {
      int grow = row0 + wm + mf * 16 + (l >> 4) * 4 + r;
      if (grow >= M) continue;
      #pragma unroll
      for (int nf = 0; nf < 4; nf++) {
        int gcol = col0 + wn + nf * 16 + (l & 15);
        float v = acc[mf][nf][r];
        if (bias) v += bias[gcol];
        if (SILU) v = siluf(v);
        if (OUT_BF16) Cb[(size_t)grow * Fo + gcol] = f2bf(v);
        else          Cf[(size_t)grow * Fo + gcol] = v;
      }
    }
  }
}

// ---------------- qkv GEMM with fused head-LN (q/k) + combo scatter (v) ----------------
__global__ __launch_bounds__(256) void k_gemm_qkv(
    const uint16_t* __restrict__ A, const uint16_t* __restrict__ BT,
    const float* __restrict__ bias, const float* __restrict__ qs,
    const float* __restrict__ qb, const float* __restrict__ ks,
    const float* __restrict__ kb, uint16_t* __restrict__ qk_b,
    uint16_t* __restrict__ combo) {
  __shared__ __align__(16) uint16_t As[128 * 72];
  __shared__ __align__(16) uint16_t Bs[128 * 72];
  int t = threadIdx.x;
  int l = t & 63;
  int row0 = blockIdx.y * 128, col0 = blockIdx.x * 128;
  int wm = ((t >> 6) >> 1) * 64, wn = ((t >> 6) & 1) * 64;
  f32x4 acc[4][4] = {};
  for (int kt = 0; kt < 128; kt += 64) {
    __syncthreads();
    #pragma unroll
    for (int i = 0; i < 4; i++) {
      int c = i * 256 + t;
      int row = c >> 3, ko = (c & 7) * 8;
      uint4 av = make_uint4(0u, 0u, 0u, 0u);
      int gr = row0 + row;
      if (gr < NN) av = *(const uint4*)&A[(size_t)gr * 128 + kt + ko];
      *(uint4*)&As[row * 72 + ko] = av;
      uint4 bw = *(const uint4*)&BT[(size_t)(col0 + row) * 128 + kt + ko];
      *(uint4*)&Bs[row * 72 + ko] = bw;
    }
    __syncthreads();
    #pragma unroll
    for (int kk = 0; kk < 64; kk += 32) {
      bf16x8 af[4], bfr[4];
      #pragma unroll
      for (int mf = 0; mf < 4; mf++)
        af[mf] = *(const bf16x8*)&As[(wm + mf * 16 + (l & 15)) * 72 + (l >> 4) * 8 + kk];
      #pragma unroll
      for (int nf = 0; nf < 4; nf++)
        bfr[nf] = *(const bf16x8*)&Bs[(wn + nf * 16 + (l & 15)) * 72 + (l >> 4) * 8 + kk];
      #pragma unroll
      for (int mf = 0; mf < 4; mf++)
        #pragma unroll
        for (int nf = 0; nf < 4; nf++)
          acc[mf][nf] = __builtin_amdgcn_mfma_f32_16x16x32_bf16(af[mf], bfr[nf], acc[mf][nf], 0, 0, 0);
    }
  }
  int d = l & 15;
  if (col0 < 256) {
    // fused per-head LN: 16 lanes of a group = 16 dims of one head, one row
    float sc_q = qs[d], bb_q = qb[d], sc_k = ks[d], bb_k = kb[d];
    #pragma unroll
    for (int mf = 0; mf < 4; mf++) {
      #pragma unroll
      for (int r = 0; r < 4; r++) {
        int grow = row0 + wm + mf * 16 + (l >> 4) * 4 + r;
        bool ok = grow < NN;
        #pragma unroll
        for (int nf = 0; nf < 4; nf++) {
          int gcol = col0 + wn + nf * 16 + d;
          float v = acc[mf][nf][r] + bias[gcol];
          float s1 = v;
          s1 += __shfl_xor(s1, 1); s1 += __shfl_xor(s1, 2);
          s1 += __shfl_xor(s1, 4); s1 += __shfl_xor(s1, 8);
          float mu = s1 * (1.f / 16.f);
          float dd = v - mu;
          float s2 = dd * dd;
          s2 += __shfl_xor(s2, 1); s2 += __shfl_xor(s2, 2);
          s2 += __shfl_xor(s2, 4); s2 += __shfl_xor(s2, 8);
          float rs = rsqrtf(s2 * (1.f / 16.f) + 1e-6f);
          bool isq = gcol < 128;
          float ov = dd * rs * (isq ? sc_q : sc_k) + (isq ? bb_q : bb_k);
          if (ok) qk_b[(size_t)grow * 256 + gcol] = f2bf(ov);
        }
      }
    }
  } else {
    #pragma unroll
    for (int mf = 0; mf < 4; mf++) {
      #pragma unroll
      for (int r = 0; r < 4; r++) {
        int grow = row0 + wm + mf * 16 + (l >> 4) * 4 + r;
        if (grow >= NN) continue;
        #pragma unroll
        for (int nf = 0; nf < 4; nf++) {
          int gcol = col0 + wn + nf * 16 + d;
          int j2 = gcol - 256, j = j2 >> 2, c = j2 & 3;
          if (c < 3)
            combo[(size_t)grow * 768 + j * 6 + c] = f2bf(acc[mf][nf][r] + bias[gcol]);
        }
      }
    }
  }
}

// ---------------- o-GEMM with fused final epilogue ----------------
// Grid (1, ceil(NN/128)); 3 sequential col-block passes (o1,o2,o3 held in regs),
// then dx = vec_dot*o2+o3, dvec = vp3*o1 + vecagg, in place on d_out.
__device__ __forceinline__ void o_pass(const float* __restrict__ A32,
                                       const uint16_t* __restrict__ BT, int row0, int cb,
                                       int t, int l, int wm, int wn,
                                       uint16_t* As, uint16_t* Bs, f32x4 (&acc)[4][4]) {
  for (int kt = 0; kt < 128; kt += 64) {
    __syncthreads();
    #pragma unroll
    for (int i = 0; i < 4; i++) {
      int c = i * 256 + t;
      int row = c >> 3, ko = (c & 7) * 8;
      uint4 av = make_uint4(0u, 0u, 0u, 0u);
      int gr = row0 + row;
      if (gr < NN) {
        float4 f0 = *(const float4*)&A32[(size_t)gr * 128 + kt + ko];
        float4 f1 = *(const float4*)&A32[(size_t)gr * 128 + kt + ko + 4];
        av = make_uint4(pk2(f0.x, f0.y), pk2(f0.z, f0.w), pk2(f1.x, f1.y), pk2(f1.z, f1.w));
      }
      *(uint4*)&As[row * 72 + ko] = av;
      uint4 bw = *(const uint4*)&BT[(size_t)(cb * 128 + row) * 128 + kt + ko];
      *(uint4*)&Bs[row * 72 + ko] = bw;
    }
    __syncthreads();
    #pragma unroll
    for (int kk = 0; kk < 64; kk += 32) {
      bf16x8 af[4], bfr[4];
      #pragma unroll
      for (int mf = 0; mf < 4; mf++)
        af[mf] = *(const bf16x8*)&As[(wm + mf * 16 + (l & 15)) * 72 + (l >> 4) * 8 + kk];
      #pragma unroll
      for (int nf = 0; nf < 4; nf++)
        bfr[nf] = *(const bf16x8*)&Bs[(wn + nf * 16 + (l & 15)) * 72 + (l >> 4) * 8 + kk];
      #pragma unroll
      for (int mf = 0; mf < 4; mf++)
        #pragma unroll
        for (int nf = 0; nf < 4; nf++)
          acc[mf][nf] = __builtin_amdgcn_mfma_f32_16x16x32_bf16(af[mf], bfr[nf], acc[mf][nf], 0, 0, 0);
    }
  }
}

__global__ __launch_bounds__(256) void k_gemm_o(
    const uint16_t* __restrict__ BT, const float* __restrict__ bo,
    const uint16_t* __restrict__ vp, float* __restrict__ dout) {
  __shared__ __align__(16) uint16_t As[128 * 72];
  __shared__ __align__(16) uint16_t Bs[128 * 72];
  float* xagg = dout;                       // A source AND dx dest (per-block rows)
  float* vecagg = dout + (size_t)NN * 128;
  int t = threadIdx.x;
  int l = t & 63;
  int row0 = blockIdx.y * 128;
  int wm = ((t >> 6) >> 1) * 64, wn = ((t >> 6) & 1) * 64;
  f32x4 acc0[4][4] = {}, acc1[4][4] = {}, acc2[4][4] = {};
  o_pass(xagg, BT, row0, 0, t, l, wm, wn, As, Bs, acc0);
  o_pass(xagg, BT, row0, 1, t, l, wm, wn, As, Bs, acc1);
  o_pass(xagg, BT, row0, 2, t, l, wm, wn, As, Bs, acc2);
  int d = l & 15;
  #pragma unroll
  for (int mf = 0; mf < 4; mf++) {
    #pragma unroll
    for (int r = 0; r < 4; r++) {
      int grow = row0 + wm + mf * 16 + (l >> 4) * 4 + r;
      if (grow >= NN) continue;
      const uint16_t* vpn = vp + (size_t)grow * 1152;
      #pragma unroll
      for (int nf = 0; nf < 4; nf++) {
        int col = wn + nf * 16 + d;
        float o1 = acc0[mf][nf][r] + bo[col];
        float o2 = acc1[mf][nf][r] + bo[128 + col];
        float o3 = acc2[mf][nf][r] + bo[256 + col];
        float vd = 0.f;
        #pragma unroll
        for (int c = 0; c < 3; c++)
          vd += bf2f(vpn[c * 384 + col]) * bf2f(vpn[c * 384 + 128 + col]);
        xagg[(size_t)grow * 128 + col] = vd * o2 + o3;
        #pragma unroll
        for (int c = 0; c < 3; c++) {
          size_t vi = ((size_t)grow * 3 + c) * 128 + col;
          vecagg[vi] = bf2f(vpn[c * 384 + 256 + col]) * o1 + vecagg[vi];
        }
      }
    }
  }
}

// ---------------- FULLY FUSED edge phase ----------------
#define MTS 516   // walk-tile row stride (shorts): slots 0=xm 1=m1 2=m2, 3 pad

__device__ __forceinline__ void mfma32(const uint16_t* As, int r0,
                                       const uint16_t* __restrict__ BT2, int cb,
                                       int wn, int l, f32x4 acc[2][2]) {
  #pragma unroll
  for (int kk = 0; kk < 2; kk++) {
    bf16x8 af[2];
    #pragma unroll
    for (int mf = 0; mf < 2; mf++)
      af[mf] = *(const bf16x8*)&As[(r0 + mf * 16 + (l & 15)) * 68 + (l >> 4) * 8 + kk * 32];
    #pragma unroll
    for (int nf = 0; nf < 2; nf++) {
      bf16x8 bv = *(const bf16x8*)&BT2[(size_t)(cb * 128 + wn + nf * 16 + (l & 15)) * 64 +
                                       (l >> 4) * 8 + kk * 32];
      #pragma unroll
      for (int mf = 0; mf < 2; mf++)
        acc[mf][nf] = __builtin_amdgcn_mfma_f32_16x16x32_bf16(af[mf], bv, acc[mf][nf], 0, 0, 0);
    }
  }
}

__device__ __forceinline__ void silu_slot(uint16_t* mt, const float bsv[2], int slot,
                                          int wn, int l, f32x4 acc[2][2]) {
  #pragma unroll
  for (int mf = 0; mf < 2; mf++)
    #pragma unroll
    for (int r = 0; r < 4; r++) {
      int row = mf * 16 + (l >> 4) * 4 + r;
      #pragma unroll
      for (int nf = 0; nf < 2; nf++) {
        int c = wn + nf * 16 + (l & 15);
        mt[row * MTS + c * 4 + slot] = f2bf(siluf(acc[mf][nf][r] + bsv[nf]));
      }
    }
}

__device__ __forceinline__ void silu_dk(uint16_t* mtd, const float bsv[2],
                                        int wn, int l, f32x4 acc[2][2]) {
  #pragma unroll
  for (int mf = 0; mf < 2; mf++)
    #pragma unroll
    for (int r = 0; r < 4; r++) {
      int row = mf * 16 + (l >> 4) * 4 + r;
      #pragma unroll
      for (int nf = 0; nf < 2; nf++) {
        int c = wn + nf * 16 + (l & 15);
        mtd[row * 140 + c] = f2bf(siluf(acc[mf][nf][r] + bsv[nf]));
      }
    }
}

__global__ __launch_bounds__(256) void k_edge_all(
    const uint16_t* __restrict__ eap, const int* __restrict__ sndp,
    const int* __restrict__ rcvp, const int* __restrict__ off,
    const float4* __restrict__ edata, const uint16_t* __restrict__ WT2,
    const float* __restrict__ Bd2, const uint16_t* __restrict__ qk_b,
    const uint16_t* __restrict__ combo, float* __restrict__ xagg,
    float* __restrict__ vecagg) {
  __shared__ __align__(16) uint16_t As[64 * 68];     // 8.7 KB
  __shared__ __align__(16) uint16_t mt[32 * MTS];    // 33 KB (xm,m1,m2 slots)
  __shared__ __align__(16) uint16_t mtd[32 * 140];   // 8.96 KB (dk)
  __shared__ float attn_l[32 * 8];                   // 1 KB
  __shared__ int sndl[64], rcvl[64], lo_g[64], hi_g[64];
  __shared__ float4 ed4[64];

  int e0 = blockIdx.x * 64;
  int t = threadIdx.x, l = t & 63, wn = (t >> 6) * 32;

  // ---- meta + A stage + bias regs ----
  if (t < 64) {
    int e = e0 + t;
    int r = rcvp[e];
    sndl[t] = sndp[e]; rcvl[t] = r;
    lo_g[t] = off[r]; hi_g[t] = off[r + 1];
    ed4[t] = edata[e];
  }
  #pragma unroll
  for (int i = 0; i < 2; i++) {
    int c = i * 256 + t;
    int row = c >> 3, ko = (c & 7) * 8;
    *(uint4*)&As[row * 68 + ko] = *(const uint4*)&eap[(size_t)(e0 + row) * 64 + ko];
  }
  float bs[4][2];
  #pragma unroll
  for (int cb = 0; cb < 4; cb++) {
    bs[cb][0] = Bd2[cb * 128 + wn + (l & 15)];
    bs[cb][1] = Bd2[cb * 128 + wn + 16 + (l & 15)];
  }
  __syncthreads();

  #pragma unroll
  for (int half = 0; half < 2; half++) {
    int r0 = half * 32;
    // ---- P1: cb0 dk -> mtd ----
    { f32x4 acc[2][2] = {}; mfma32(As, r0, WT2, 0, wn, l, acc); silu_dk(mtd, bs[0], wn, l, acc); }
    __syncthreads();
    // ---- P2: q/k loads early, cb1-3 MFMA hide them, then attn dot ----
    {
      int el = t >> 3, h = t & 7;
      int ge = r0 + el;
      int rn = rcvl[ge], sn = sndl[ge];
      const uint16_t* qb_ = qk_b + (size_t)rn * 256 + h * 16;
      const uint16_t* kb_ = qk_b + (size_t)sn * 256 + 128 + h * 16;
      uint4 q0 = *(const uint4*)qb_;
      uint4 q1 = *(const uint4*)(qb_ + 8);
      uint4 k0 = *(const uint4*)kb_;
      uint4 k1 = *(const uint4*)(kb_ + 8);
      { f32x4 acc[2][2] = {}; mfma32(As, r0, WT2, 1, wn, l, acc); silu_slot(mt, bs[1], 0, wn, l, acc); }
      { f32x4 acc[2][2] = {}; mfma32(As, r0, WT2, 2, wn, l, acc); silu_slot(mt, bs[2], 1, wn, l, acc); }
      { f32x4 acc[2][2] = {}; mfma32(As, r0, WT2, 3, wn, l, acc); silu_slot(mt, bs[3], 2, wn, l, acc); }
      const uint32_t* dp = (const uint32_t*)&mtd[el * 140 + h * 16];
      uint32_t qa[8] = {q0.x, q0.y, q0.z, q0.w, q1.x, q1.y, q1.z, q1.w};
      uint32_t ka[8] = {k0.x, k0.y, k0.z, k0.w, k1.x, k1.y, k1.z, k1.w};
      float dot = 0.f;
      #pragma unroll
      for (int j = 0; j < 8; j++) dot += prod2(qa[j], ka[j], dp[j]);
      attn_l[el * 8 + h] = siluf(dot) * ed4[ge].w;
    }
    __syncthreads();
    // ---- P3: merged walk; 12B combo gather per (edge,col) ----
    {
      int col = t & 127, sub = t >> 7;
      int i0 = r0 + sub * 16, i1 = i0 + 16;
      int ha = col >> 4;
      float accx = 0.f, a0 = 0.f, a1 = 0.f, a2 = 0.f;
      #pragma unroll 8
      for (int i = i0; i < i1; i++) {
        int li = i - r0;
        int n = rcvl[i], s = sndl[i];
        const uint16_t* cp = &combo[(size_t)s * 768 + col * 6];
        uint32_t u0 = *(const uint32_t*)cp;        // v0|v1
        uint32_t u1 = *(const uint32_t*)(cp + 2);  // v2|w0
        uint32_t u2 = *(const uint32_t*)(cp + 4);  // w1|w2
        uint2 mr = *(const uint2*)&mt[li * MTS + col * 4];
        float a = attn_l[li * 8 + ha];
        float xmv = bf2f(mr.x & 0xffffu), m1v = bf2f(mr.x >> 16), m2v = bf2f(mr.y & 0xffffu);
        accx += bf2f(u0 & 0xffffu) * xmv * a;
        float mm1 = bf2f(u0 >> 16) * m1v;
        float mm2 = bf2f(u1 & 0xffffu) * m2v;
        float4 ev = ed4[i];
        a0 += bf2f(u1 >> 16)     * mm1 + ev.x * mm2;
        a1 += bf2f(u2 & 0xffffu) * mm1 + ev.y * mm2;
        a2 += bf2f(u2 >> 16)     * mm1 + ev.z * mm2;
        if (i == i1 - 1 || rcvl[i + 1] != n) {
          bool cont = (lo_g[i] >= e0 + i0) && (hi_g[i] <= e0 + i1);
          float* dx_ = &xagg[(size_t)n * 128 + col];
          float* d0 = &vecagg[((size_t)n * 3 + 0) * 128 + col];
          float* d1 = &vecagg[((size_t)n * 3 + 1) * 128 + col];
          float* d2 = &vecagg[((size_t)n * 3 + 2) * 128 + col];
          if (cont) { *dx_ = accx; *d0 = a0; *d1 = a1; *d2 = a2; }
          else { atomicAdd(dx_, accx); atomicAdd(d0, a0); atomicAdd(d1, a1); atomicAdd(d2, a2); }
          accx = a0 = a1 = a2 = 0.f;
        }
      }
    }
    __syncthreads();
  }
}

static inline int cdiv_i(long long a, long long b) { return (int)((a + b - 1) / b); }

extern "C" void kernel_launch(void* const* d_in, const int* in_sizes, int n_in,
                              void* d_out, int out_size, void* d_ws, size_t ws_size,
                              hipStream_t stream) {
  const float* x    = (const float*)d_in[0];
  const float* vec  = (const float*)d_in[1];
  const float* ew   = (const float*)d_in[2];
  const float* ea   = (const float*)d_in[3];
  const float* evec = (const float*)d_in[4];
  const int*   snd  = (const int*)d_in[5];
  const int*   rcv  = (const int*)d_in[6];
  const float* ln_s = (const float*)d_in[7];
  const float* ln_b = (const float*)d_in[8];
  const float* Wq = (const float*)d_in[9];   const float* bq = (const float*)d_in[10];
  const float* Wk = (const float*)d_in[11];  const float* bk = (const float*)d_in[12];
  const float* Wv = (const float*)d_in[13];  const float* bv = (const float*)d_in[14];
  const float* Wvec = (const float*)d_in[15];
  const float* Wdk = (const float*)d_in[16]; const float* bdk = (const float*)d_in[17];
  const float* Wdv = (const float*)d_in[18]; const float* bdv = (const float*)d_in[19];
  const float* Wo = (const float*)d_in[20];  const float* bo = (const float*)d_in[21];
  const float* qln_s = (const float*)d_in[22]; const float* qln_b = (const float*)d_in[23];
  const float* kln_s = (const float*)d_in[24]; const float* kln_b = (const float*)d_in[25];
  (void)in_sizes; (void)n_in; (void)ws_size;

  uint8_t* p = (uint8_t*)d_ws;
  auto alloc = [&](size_t bytes) -> uint8_t* {
    uint8_t* r = p; p += (bytes + 255) & ~(size_t)255; return r;
  };
  uint16_t* WTqkv = (uint16_t*)alloc(768 * 128 * 2);
  float*    Bqkv  = (float*)alloc(768 * 4);
  uint16_t* WTvec = (uint16_t*)alloc(384 * 128 * 2);
  uint16_t* WTdkv = (uint16_t*)alloc(512 * 64 * 2);
  float*    Bdkv  = (float*)alloc(512 * 4);
  uint16_t* WTo   = (uint16_t*)alloc(384 * 128 * 2);
  int*      deg   = (int*)alloc(NN * 4);
  int*      off   = (int*)alloc((NN + 1) * 4);
  int*      cur   = (int*)alloc(NN * 4);
  int*      bsum  = (int*)alloc(256 * 4);
  int*      perm  = (int*)alloc((size_t)NE * 4);
  int*      sndp  = (int*)alloc((size_t)NE * 4);
  int*      rcvp  = (int*)alloc((size_t)NE * 4);
  float4*   edata = (float4*)alloc((size_t)NE * 16);
  uint16_t* ea_perm = (uint16_t*)alloc((size_t)NE * 64 * 2);
  uint16_t* xn_b  = (uint16_t*)alloc((size_t)NN * 128 * 2);
  uint16_t* combo = (uint16_t*)alloc((size_t)NN * 768 * 2);
  uint16_t* qk_b  = (uint16_t*)alloc((size_t)NN * 256 * 2);
  uint16_t* vp    = (uint16_t*)alloc((size_t)NN * 3 * 384 * 2);

  float* xagg   = (float*)d_out;
  float* vecagg = (float*)d_out + (size_t)NN * 128;

  hipMemsetAsync(d_out, 0, (size_t)out_size * 4, stream);

  // ---- weights prep (1 launch) ----
  k_prep<<<cdiv_i(98304 + 49152 + 32768 + 49152 + 1280, 256), 256, 0, stream>>>(
      Wq, Wk, Wv, Wvec, Wdk, Wdv, Wo, bq, bk, bv, bdk, bdv,
      WTqkv, WTvec, WTdkv, WTo, Bqkv, Bdkv);

  // ---- edge sort by receiver ----
  int NSB = cdiv_i(NN, 256);
  hipMemsetAsync(deg, 0, NN * 4, stream);
  k_hist<<<cdiv_i(NE, 256), 256, 0, stream>>>(rcv, deg);
  k_scan1<<<NSB, 256, 0, stream>>>(deg, bsum);
  k_scan2<<<1, 64, 0, stream>>>(bsum, NSB, off);
  k_scan3<<<NSB, 256, 0, stream>>>(deg, bsum, off, cur);
  k_scatter<<<cdiv_i(NE, 256), 256, 0, stream>>>(rcv, cur, perm);
  k_permute<<<cdiv_i((long long)NE * 16, 256), 256, 0, stream>>>(ea, perm, snd, rcv, ew, evec,
                                                                 ea_perm, sndp, rcvp, edata);

  // ---- node pre (LN + combo w-slots) ----
  k_node_pre<<<5000 + cdiv_i((long long)NN * 128, 256), 256, 0, stream>>>(
      x, ln_s, ln_b, vec, xn_b, combo);

  // qkv GEMM: q/k with fused head-LN -> qk_b; v -> combo slots 0-2
  { dim3 g(6, cdiv_i(NN, 128));
    k_gemm_qkv<<<g, 256, 0, stream>>>(xn_b, WTqkv, Bqkv, qln_s, qln_b, kln_s, kln_b,
                                      qk_b, combo); }

  // vp = vec @ Wvec (f32 A staged to bf16; bf16 out)
  { dim3 g(384 / 128, cdiv_i((long long)NN * 3, 128));
    k_gemm<128, true, false, true><<<g, 256, 0, stream>>>(vec, WTvec, nullptr, vp, NN * 3, 384); }

  // ---- fully fused edge phase ----
  k_edge_all<<<NE / 64, 256, 0, stream>>>(ea_perm, sndp, rcvp, off, edata, WTdkv, Bdkv,
                                          qk_b, combo, xagg, vecagg);

  // ---- o-GEMM with fused final epilogue (in-place on d_out) ----
  { dim3 g(1, cdiv_i(NN, 128));
    k_gemm_o<<<g, 256, 0, stream>>>(WTo, bo, vp, (float*)d_out); }
}

// Round 13
// 350.387 us; speedup vs baseline: 1.0166x; 1.0166x over previous
//
#include <hip/hip_runtime.h>
#include <stdint.h>

#define NN 20000
#define NE 200000   // == 3125 * 64 exactly (k_edge_all assumes this)
// H=128, NH=8, HD=16, RBF=64

typedef __attribute__((ext_vector_type(8))) short bf16x8;
typedef __attribute__((ext_vector_type(4))) float f32x4;

__device__ __forceinline__ float bf2f(uint32_t u) {
  union { uint32_t i; float f; } v; v.i = u << 16; return v.f;
}
__device__ __forceinline__ uint16_t f2bf(float f) {
  union { float f; uint32_t i; } v; v.f = f;
  return (uint16_t)((v.i + 0x7fffu + ((v.i >> 16) & 1u)) >> 16);
}
__device__ __forceinline__ uint32_t pk2(float lo, float hi) {
  return (uint32_t)f2bf(lo) | ((uint32_t)f2bf(hi) << 16);
}
__device__ __forceinline__ float siluf(float x) { return x / (1.f + __expf(-x)); }
__device__ __forceinline__ float prod2(uint32_t q2, uint32_t k2, uint32_t d2) {
  return bf2f(q2 & 0xffffu) * bf2f(k2 & 0xffffu) * bf2f(d2 & 0xffffu)
       + bf2f(q2 >> 16) * bf2f(k2 >> 16) * bf2f(d2 >> 16);
}

// ---------------- consolidated weight prep (one launch) ----------------
// WTqkv [768][128]: rows 0-255 = q|k; rows 256-767 v INTERLEAVED
// (row 256 + j*4 + c, j=h*16+d, c=0..2 from orig col h*48+c*16+d, c==3 pad).
// WTdkv2 [512][64] column-reordered: dk | xm | m1 | m2.
__global__ void k_prep(const float* __restrict__ Wq, const float* __restrict__ Wk,
                       const float* __restrict__ Wv, const float* __restrict__ Wvec,
                       const float* __restrict__ Wdk, const float* __restrict__ Wdv,
                       const float* __restrict__ Wo, const float* __restrict__ bq,
                       const float* __restrict__ bk, const float* __restrict__ bv,
                       const float* __restrict__ bdk, const float* __restrict__ bdv,
                       uint16_t* __restrict__ WTqkv, uint16_t* __restrict__ WTvec,
                       uint16_t* __restrict__ WTdkv2, uint16_t* __restrict__ WTo,
                       float* __restrict__ Bqkv, float* __restrict__ Bdkv2) {
  int idx = blockIdx.x * 256 + threadIdx.x;
  if (idx < 98304) {                       // WTqkv [768][128]
    int rr = idx >> 7, k = idx & 127;
    float v;
    if (rr < 128)      v = Wq[k * 128 + rr];
    else if (rr < 256) v = Wk[k * 128 + rr - 128];
    else {
      int j2 = rr - 256, j = j2 >> 2, c = j2 & 3;
      v = (c < 3) ? Wv[k * 384 + (j >> 4) * 48 + c * 16 + (j & 15)] : 0.f;
    }
    WTqkv[idx] = f2bf(v);
    return;
  }
  idx -= 98304;
  if (idx < 49152) {                       // WTvec [384][128]
    int c = idx >> 7, k = idx & 127;
    WTvec[idx] = f2bf(Wvec[k * 384 + c]);
    return;
  }
  idx -= 49152;
  if (idx < 32768) {                       // WTdkv2 [512][64], reordered
    int rr = idx >> 6, k = idx & 63;
    float v;
    if (rr < 128) v = Wdk[k * 128 + rr];
    else {
      int j = rr - 128, p = j >> 7, hd = j & 127;
      v = Wdv[k * 384 + (hd >> 4) * 48 + p * 16 + (hd & 15)];
    }
    WTdkv2[idx] = f2bf(v);
    return;
  }
  idx -= 32768;
  if (idx < 49152) {                       // WTo [384][128]
    int c = idx >> 7, k = idx & 127;
    WTo[idx] = f2bf(Wo[k * 384 + c]);
    return;
  }
  idx -= 49152;
  if (idx < 768) {                         // Bqkv [768]
    if (idx < 128)      Bqkv[idx] = bq[idx];
    else if (idx < 256) Bqkv[idx] = bk[idx - 128];
    else {
      int j2 = idx - 256, j = j2 >> 2, c = j2 & 3;
      Bqkv[idx] = (c < 3) ? bv[(j >> 4) * 48 + c * 16 + (j & 15)] : 0.f;
    }
  } else if (idx < 1280) {
    int t = idx - 768;
    if (t < 128) Bdkv2[t] = bdk[t];
    else {
      int j = t - 128, p = j >> 7, hd = j & 127;
      Bdkv2[t] = bdv[(hd >> 4) * 48 + p * 16 + (hd & 15)];
    }
  }
}

// ---------------- node pre: LN(x)->bf16 + vec GEMM-layout + vec walk-layout ----------------
__global__ void k_node_pre(const float* __restrict__ x, const float* __restrict__ s,
                           const float* __restrict__ b, const float* __restrict__ vec,
                           uint16_t* __restrict__ xn_b, uint16_t* __restrict__ vec_b,
                           uint16_t* __restrict__ vec_w) {
  if (blockIdx.x < 5000) {
    int gt = blockIdx.x * 256 + threadIdx.x;
    int node = gt >> 6, lane = gt & 63;
    if (node >= NN) return;
    const float* row = x + (size_t)node * 128;
    float2 v = *(const float2*)&row[lane * 2];
    float sum = v.x + v.y, sq = v.x * v.x + v.y * v.y;
    #pragma unroll
    for (int off = 32; off; off >>= 1) { sum += __shfl_xor(sum, off); sq += __shfl_xor(sq, off); }
    float mu = sum * (1.f / 128.f);
    float var = sq * (1.f / 128.f) - mu * mu;
    float rs = rsqrtf(var + 1e-6f);
    float o0 = (v.x - mu) * rs * s[lane * 2] + b[lane * 2];
    float o1 = (v.y - mu) * rs * s[lane * 2 + 1] + b[lane * 2 + 1];
    ((uint32_t*)xn_b)[(size_t)node * 64 + lane] = pk2(o0, o1);
  } else if (blockIdx.x < 20000) {
    int i = (blockIdx.x - 5000) * 256 + threadIdx.x;   // NN*3*64 pairs
    float2 v = ((const float2*)vec)[i];
    ((uint32_t*)vec_b)[i] = pk2(v.x, v.y);
  } else {
    int i = (blockIdx.x - 20000) * 256 + threadIdx.x;  // NN*128 triples
    int n = i >> 7, j = i & 127;
    const float* vr = vec + (size_t)n * 384 + j;
    uint2 o;
    o.x = pk2(vr[0], vr[128]);
    o.y = pk2(vr[256], 0.f);
    *(uint2*)&vec_w[(size_t)n * 512 + j * 4] = o;
  }
}

__global__ void k_cast_bf16(const float* __restrict__ src, uint16_t* __restrict__ dst, int npairs) {
  int i = blockIdx.x * 256 + threadIdx.x;
  if (i >= npairs) return;
  float2 v = ((const float2*)src)[i];
  ((uint32_t*)dst)[i] = pk2(v.x, v.y);
}

// ---------------- edge sort by receiver (counting sort, parallel scan) ----------------
__global__ void k_hist(const int* __restrict__ rcv, int* __restrict__ deg) {
  int e = blockIdx.x * 256 + threadIdx.x;
  if (e < NE) atomicAdd(&deg[rcv[e]], 1);
}

__global__ void k_scan1(const int* __restrict__ deg, int* __restrict__ bsum) {
  __shared__ int ws[4];
  int i = blockIdx.x * 256 + threadIdx.x;
  int x = (i < NN) ? deg[i] : 0;
  #pragma unroll
  for (int d = 32; d; d >>= 1) x += __shfl_xor(x, d);
  if ((threadIdx.x & 63) == 0) ws[threadIdx.x >> 6] = x;
  __syncthreads();
  if (threadIdx.x == 0) bsum[blockIdx.x] = ws[0] + ws[1] + ws[2] + ws[3];
}

__global__ void k_scan2(int* __restrict__ bsum, int nb, int* __restrict__ off) {
  int lane = threadIdx.x;
  int carry = 0;
  for (int base = 0; base < nb; base += 64) {
    int i = base + lane;
    int x = (i < nb) ? bsum[i] : 0;
    int v = x;
    #pragma unroll
    for (int d = 1; d < 64; d <<= 1) { int y = __shfl_up(v, d); if (lane >= d) v += y; }
    if (i < nb) bsum[i] = carry + v - x;
    carry += __shfl(v, 63);
  }
  if (lane == 0) off[NN] = carry;
}

__global__ void k_scan3(const int* __restrict__ deg, const int* __restrict__ bsum,
                        int* __restrict__ off, int* __restrict__ cur) {
  __shared__ int ws[4];
  int t = threadIdx.x, lane = t & 63, w = t >> 6;
  int i = blockIdx.x * 256 + t;
  int x = (i < NN) ? deg[i] : 0;
  int v = x;
  #pragma unroll
  for (int d = 1; d < 64; d <<= 1) { int y = __shfl_up(v, d); if (lane >= d) v += y; }
  if (lane == 63) ws[w] = v;
  __syncthreads();
  int wadd = 0;
  for (int j = 0; j < w; j++) wadd += ws[j];
  int excl = bsum[blockIdx.x] + wadd + v - x;
  if (i < NN) { off[i] = excl; cur[i] = excl; }
}

__global__ void k_scatter(const int* __restrict__ rcv, int* __restrict__ cur,
                          int* __restrict__ perm) {
  int e = blockIdx.x * 256 + threadIdx.x;
  if (e >= NE) return;
  int pos = atomicAdd(&cur[rcv[e]], 1);
  perm[pos] = e;
}

// gather+cast edge_attr rows in permuted order; also permute snd/rcv and
// pack (evec.xyz, cutoff(ew)) into edata
__global__ void k_permute(const float* __restrict__ ea, const int* __restrict__ perm,
                          const int* __restrict__ snd, const int* __restrict__ rcv,
                          const float* __restrict__ ew, const float* __restrict__ evec,
                          uint16_t* __restrict__ ea_perm, int* __restrict__ sndp,
                          int* __restrict__ rcvp, float4* __restrict__ edata) {
  int idx = blockIdx.x * 256 + threadIdx.x;   // 16 threads per edge
  if (idx >= NE * 16) return;
  int i = idx >> 4, j = idx & 15;
  int e = perm[i];
  float4 v = *(const float4*)&ea[(size_t)e * 64 + j * 4];
  uint2 o;
  o.x = pk2(v.x, v.y);
  o.y = pk2(v.z, v.w);
  *(uint2*)&ea_perm[(size_t)i * 64 + j * 4] = o;
  if (j == 0) {
    sndp[i] = snd[e];
    rcvp[i] = rcv[e];
    float w = ew[e];
    float cut = (w < 5.f) ? 0.5f * (__cosf(w * 0.628318530717958648f) + 1.f) : 0.f;
    edata[i] = make_float4(evec[e * 3], evec[e * 3 + 1], evec[e * 3 + 2], cut);
  }
}

// ---------------- bf16 MFMA GEMM: C = act(A @ BT^T + bias) ----------------
template <int KTOT, bool OUT_BF16, bool SILU>
__global__ __launch_bounds__(256) void k_gemm(const uint16_t* __restrict__ A,
                                              const uint16_t* __restrict__ BT,
                                              const float* __restrict__ bias,
                                              void* __restrict__ Cout, int M, int Fo) {
  __shared__ __align__(16) uint16_t As[128 * 72];
  __shared__ __align__(16) uint16_t Bs[128 * 72];
  int t = threadIdx.x;
  int l = t & 63;
  int row0 = blockIdx.y * 128, col0 = blockIdx.x * 128;
  int wm = ((t >> 6) >> 1) * 64, wn = ((t >> 6) & 1) * 64;
  f32x4 acc[4][4] = {};
  for (int kt = 0; kt < KTOT; kt += 64) {
    __syncthreads();
    #pragma unroll
    for (int i = 0; i < 4; i++) {
      int c = i * 256 + t;
      int row = c >> 3, ko = (c & 7) * 8;
      uint4 av = make_uint4(0u, 0u, 0u, 0u);
      int gr = row0 + row;
      if (gr < M) av = *(const uint4*)&A[(size_t)gr * KTOT + kt + ko];
      *(uint4*)&As[row * 72 + ko] = av;
      uint4 bw = *(const uint4*)&BT[(size_t)(col0 + row) * KTOT + kt + ko];
      *(uint4*)&Bs[row * 72 + ko] = bw;
    }
    __syncthreads();
    #pragma unroll
    for (int kk = 0; kk < 64; kk += 32) {
      bf16x8 af[4], bfr[4];
      #pragma unroll
      for (int mf = 0; mf < 4; mf++)
        af[mf] = *(const bf16x8*)&As[(wm + mf * 16 + (l & 15)) * 72 + (l >> 4) * 8 + kk];
      #pragma unroll
      for (int nf = 0; nf < 4; nf++)
        bfr[nf] = *(const bf16x8*)&Bs[(wn + nf * 16 + (l & 15)) * 72 + (l >> 4) * 8 + kk];
      #pragma unroll
      for (int mf = 0; mf < 4; mf++)
        #pragma unroll
        for (int nf = 0; nf < 4; nf++)
          acc[mf][nf] = __builtin_amdgcn_mfma_f32_16x16x32_bf16(af[mf], bfr[nf], acc[mf][nf], 0, 0, 0);
    }
  }
  float* Cf = (float*)Cout;
  uint16_t* Cb = (uint16_t*)Cout;
  #pragma unroll
  for (int mf = 0; mf < 4; mf++) {
    #pragma unroll
    for (int r = 0; r < 4; r++) {
      int grow = row0 + wm + mf * 16 + (l >> 4) * 4 + r;
      if (grow >= M) continue;
      #pragma unroll
      for (int nf = 0; nf < 4; nf++) {
        int gcol = col0 + wn + nf * 16 + (l & 15);
        float v = acc[mf][nf][r];
        if (bias) v += bias[gcol];
        if (SILU) v = siluf(v);
        if (OUT_BF16) Cb[(size_t)grow * Fo + gcol] = f2bf(v);
        else          Cf[(size_t)grow * Fo + gcol] = v;
      }
    }
  }
}

// ---------------- per-head LN on q/k (bf16 in/out, qkv row stride 768) ----------------
__global__ void k_headln(const uint16_t* __restrict__ qkv, const float* __restrict__ qs,
                         const float* __restrict__ qb, const float* __restrict__ ks,
                         const float* __restrict__ kb, uint16_t* __restrict__ out) {
  int idx = blockIdx.x * 256 + threadIdx.x;
  if (idx >= NN * 16) return;
  int n = idx >> 4, ph = idx & 15, part = ph >> 3, h = ph & 7;
  const uint16_t* src = qkv + (size_t)n * 768 + part * 128 + h * 16;
  float v[16], sum = 0.f;
  #pragma unroll
  for (int i = 0; i < 16; i++) { v[i] = bf2f(src[i]); sum += v[i]; }
  float mu = sum * (1.f / 16.f), var = 0.f;
  #pragma unroll
  for (int i = 0; i < 16; i++) { float dd = v[i] - mu; var += dd * dd; }
  float rs = rsqrtf(var * (1.f / 16.f) + 1e-6f);
  const float* sc = part ? ks : qs;
  const float* bb = part ? kb : qb;
  uint16_t* dst = out + (size_t)n * 256 + part * 128 + h * 16;
  #pragma unroll
  for (int i = 0; i < 16; i++) dst[i] = f2bf((v[i] - mu) * rs * sc[i] + bb[i]);
}

// ---------------- FULLY FUSED edge phase (separate dk plane; 5 barriers) ----------------
#define MTS 516   // mt row stride in shorts: slots 0=xm 1=m1 2=m2 (slot 3 unused)

__device__ __forceinline__ void mfma32(const uint16_t* As, int r0,
                                       const uint16_t* __restrict__ BT2, int cb,
                                       int wn, int l, f32x4 acc[2][2]) {
  #pragma unroll
  for (int kk = 0; kk < 2; kk++) {
    bf16x8 af[2];
    #pragma unroll
    for (int mf = 0; mf < 2; mf++)
      af[mf] = *(const bf16x8*)&As[(r0 + mf * 16 + (l & 15)) * 68 + (l >> 4) * 8 + kk * 32];
    #pragma unroll
    for (int nf = 0; nf < 2; nf++) {
      bf16x8 bv = *(const bf16x8*)&BT2[(size_t)(cb * 128 + wn + nf * 16 + (l & 15)) * 64 +
                                       (l >> 4) * 8 + kk * 32];
      #pragma unroll
      for (int mf = 0; mf < 2; mf++)
        acc[mf][nf] = __builtin_amdgcn_mfma_f32_16x16x32_bf16(af[mf], bv, acc[mf][nf], 0, 0, 0);
    }
  }
}

__device__ __forceinline__ void silu_slot(uint16_t* mt, const float bsv[2], int slot,
                                          int wn, int l, f32x4 acc[2][2]) {
  #pragma unroll
  for (int mf = 0; mf < 2; mf++)
    #pragma unroll
    for (int r = 0; r < 4; r++) {
      int row = mf * 16 + (l >> 4) * 4 + r;
      #pragma unroll
      for (int nf = 0; nf < 2; nf++) {
        int c = wn + nf * 16 + (l & 15);
        mt[row * MTS + c * 4 + slot] = f2bf(siluf(acc[mf][nf][r] + bsv[nf]));
      }
    }
}

__device__ __forceinline__ void silu_dk(uint16_t* mtd, const float bsv[2],
                                        int wn, int l, f32x4 acc[2][2]) {
  #pragma unroll
  for (int mf = 0; mf < 2; mf++)
    #pragma unroll
    for (int r = 0; r < 4; r++) {
      int row = mf * 16 + (l >> 4) * 4 + r;
      #pragma unroll
      for (int nf = 0; nf < 2; nf++) {
        int c = wn + nf * 16 + (l & 15);
        mtd[row * 140 + c] = f2bf(siluf(acc[mf][nf][r] + bsv[nf]));
      }
    }
}

__global__ __launch_bounds__(256) void k_edge_all(
    const uint16_t* __restrict__ eap, const int* __restrict__ sndp,
    const int* __restrict__ rcvp, const int* __restrict__ off,
    const float4* __restrict__ edata, const uint16_t* __restrict__ WT2,
    const float* __restrict__ Bd2, const uint16_t* __restrict__ qk_b,
    const uint16_t* __restrict__ qkv_b, const uint16_t* __restrict__ vec_w,
    float* __restrict__ xagg, float* __restrict__ vecagg) {
  __shared__ __align__(16) uint16_t As[64 * 68];     // 8.7 KB
  __shared__ __align__(16) uint16_t mt[32 * MTS];    // 33 KB; slots 0=xm 1=m1 2=m2
  __shared__ __align__(16) uint16_t mtd[32 * 140];   // 8.96 KB (dk, conflict-free attn reads)
  __shared__ float attn_l[32 * 8];                   // 1 KB
  __shared__ int sndl[64], rcvl[64], lo_g[64], hi_g[64];
  __shared__ float4 ed4[64];

  int e0 = blockIdx.x * 64;
  int t = threadIdx.x, l = t & 63, wn = (t >> 6) * 32;

  // ---- meta + A stage + bias regs ----
  if (t < 64) {
    int e = e0 + t;
    int r = rcvp[e];
    sndl[t] = sndp[e]; rcvl[t] = r;
    lo_g[t] = off[r]; hi_g[t] = off[r + 1];
    ed4[t] = edata[e];
  }
  #pragma unroll
  for (int i = 0; i < 2; i++) {
    int c = i * 256 + t;
    int row = c >> 3, ko = (c & 7) * 8;
    *(uint4*)&As[row * 68 + ko] = *(const uint4*)&eap[(size_t)(e0 + row) * 64 + ko];
  }
  float bs[4][2];
  #pragma unroll
  for (int cb = 0; cb < 4; cb++) {
    bs[cb][0] = Bd2[cb * 128 + wn + (l & 15)];
    bs[cb][1] = Bd2[cb * 128 + wn + 16 + (l & 15)];
  }
  __syncthreads();

  #pragma unroll
  for (int half = 0; half < 2; half++) {
    int r0 = half * 32;
    // ---- P1: cb0 dk -> mtd ----
    { f32x4 acc[2][2] = {}; mfma32(As, r0, WT2, 0, wn, l, acc); silu_dk(mtd, bs[0], wn, l, acc); }
    __syncthreads();
    // ---- P2: q/k loads early, cb1-3 MFMA hide them, then attn dot ----
    {
      int el = t >> 3, h = t & 7;
      int ge = r0 + el;
      int rn = rcvl[ge], sn = sndl[ge];
      const uint16_t* qb_ = qk_b + (size_t)rn * 256 + h * 16;
      const uint16_t* kb_ = qk_b + (size_t)sn * 256 + 128 + h * 16;
      uint4 q0 = *(const uint4*)qb_;
      uint4 q1 = *(const uint4*)(qb_ + 8);
      uint4 k0 = *(const uint4*)kb_;
      uint4 k1 = *(const uint4*)(kb_ + 8);
      { f32x4 acc[2][2] = {}; mfma32(As, r0, WT2, 1, wn, l, acc); silu_slot(mt, bs[1], 0, wn, l, acc); }
      { f32x4 acc[2][2] = {}; mfma32(As, r0, WT2, 2, wn, l, acc); silu_slot(mt, bs[2], 1, wn, l, acc); }
      { f32x4 acc[2][2] = {}; mfma32(As, r0, WT2, 3, wn, l, acc); silu_slot(mt, bs[3], 2, wn, l, acc); }
      const uint32_t* dp = (const uint32_t*)&mtd[el * 140 + h * 16];
      uint32_t qa[8] = {q0.x, q0.y, q0.z, q0.w, q1.x, q1.y, q1.z, q1.w};
      uint32_t ka[8] = {k0.x, k0.y, k0.z, k0.w, k1.x, k1.y, k1.z, k1.w};
      float dot = 0.f;
      #pragma unroll
      for (int j = 0; j < 8; j++) dot += prod2(qa[j], ka[j], dp[j]);
      attn_l[el * 8 + h] = siluf(dot) * ed4[ge].w;
    }
    __syncthreads();
    // ---- P3: merged walk: thread = (col, 16-edge sub-window); 2 wide gathers/iter ----
    {
      int col = t & 127, sub = t >> 7;
      int i0 = r0 + sub * 16, i1 = i0 + 16;
      int ha = col >> 4;
      float accx = 0.f, a0 = 0.f, a1 = 0.f, a2 = 0.f;
      #pragma unroll 8
      for (int i = i0; i < i1; i++) {
        int li = i - r0;
        int n = rcvl[i], s = sndl[i];
        uint2 vt = *(const uint2*)&qkv_b[(size_t)s * 768 + 256 + col * 4];
        uint2 wt = *(const uint2*)&vec_w[(size_t)s * 512 + col * 4];
        uint2 mr = *(const uint2*)&mt[li * MTS + col * 4];
        float a = attn_l[li * 8 + ha];
        float xmv = bf2f(mr.x & 0xffffu), m1v = bf2f(mr.x >> 16), m2v = bf2f(mr.y & 0xffffu);
        accx += bf2f(vt.x & 0xffffu) * xmv * a;
        float mm1 = bf2f(vt.x >> 16) * m1v;
        float mm2 = bf2f(vt.y & 0xffffu) * m2v;
        float4 ev = ed4[i];
        a0 += bf2f(wt.x & 0xffffu) * mm1 + ev.x * mm2;
        a1 += bf2f(wt.x >> 16)     * mm1 + ev.y * mm2;
        a2 += bf2f(wt.y & 0xffffu) * mm1 + ev.z * mm2;
        if (i == i1 - 1 || rcvl[i + 1] != n) {
          bool cont = (lo_g[i] >= e0 + i0) && (hi_g[i] <= e0 + i1);
          float* dx_ = &xagg[(size_t)n * 128 + col];
          float* d0 = &vecagg[((size_t)n * 3 + 0) * 128 + col];
          float* d1 = &vecagg[((size_t)n * 3 + 1) * 128 + col];
          float* d2 = &vecagg[((size_t)n * 3 + 2) * 128 + col];
          if (cont) { *dx_ = accx; *d0 = a0; *d1 = a1; *d2 = a2; }
          else { atomicAdd(dx_, accx); atomicAdd(d0, a0); atomicAdd(d1, a1); atomicAdd(d2, a2); }
          accx = a0 = a1 = a2 = 0.f;
        }
      }
    }
    __syncthreads();
  }
}

// ---------------- final ----------------
__global__ void k_final(const float* __restrict__ o, const uint16_t* __restrict__ vp,
                        float* __restrict__ dx, float* __restrict__ dvec) {
  int idx = blockIdx.x * 256 + threadIdx.x;
  if (idx >= NN * 128) return;
  int n = idx >> 7, j = idx & 127;
  const float* op = o + (size_t)n * 384;
  float o1 = op[j], o2 = op[128 + j], o3 = op[256 + j];
  const uint16_t* vpn = vp + (size_t)n * 3 * 384;
  float vd = 0.f;
  #pragma unroll
  for (int c = 0; c < 3; c++)
    vd += bf2f(vpn[c * 384 + j]) * bf2f(vpn[c * 384 + 128 + j]);
  dx[idx] = vd * o2 + o3;
  #pragma unroll
  for (int c = 0; c < 3; c++) {
    size_t vi = ((size_t)n * 3 + c) * 128 + j;
    dvec[vi] = bf2f(vpn[c * 384 + 256 + j]) * o1 + dvec[vi];
  }
}

static inline int cdiv_i(long long a, long long b) { return (int)((a + b - 1) / b); }

extern "C" void kernel_launch(void* const* d_in, const int* in_sizes, int n_in,
                              void* d_out, int out_size, void* d_ws, size_t ws_size,
                              hipStream_t stream) {
  const float* x    = (const float*)d_in[0];
  const float* vec  = (const float*)d_in[1];
  const float* ew   = (const float*)d_in[2];
  const float* ea   = (const float*)d_in[3];
  const float* evec = (const float*)d_in[4];
  const int*   snd  = (const int*)d_in[5];
  const int*   rcv  = (const int*)d_in[6];
  const float* ln_s = (const float*)d_in[7];
  const float* ln_b = (const float*)d_in[8];
  const float* Wq = (const float*)d_in[9];   const float* bq = (const float*)d_in[10];
  const float* Wk = (const float*)d_in[11];  const float* bk = (const float*)d_in[12];
  const float* Wv = (const float*)d_in[13];  const float* bv = (const float*)d_in[14];
  const float* Wvec = (const float*)d_in[15];
  const float* Wdk = (const float*)d_in[16]; const float* bdk = (const float*)d_in[17];
  const float* Wdv = (const float*)d_in[18]; const float* bdv = (const float*)d_in[19];
  const float* Wo = (const float*)d_in[20];  const float* bo = (const float*)d_in[21];
  const float* qln_s = (const float*)d_in[22]; const float* qln_b = (const float*)d_in[23];
  const float* kln_s = (const float*)d_in[24]; const float* kln_b = (const float*)d_in[25];
  (void)in_sizes; (void)n_in; (void)ws_size;

  uint8_t* p = (uint8_t*)d_ws;
  auto alloc = [&](size_t bytes) -> uint8_t* {
    uint8_t* r = p; p += (bytes + 255) & ~(size_t)255; return r;
  };
  uint16_t* WTqkv = (uint16_t*)alloc(768 * 128 * 2);
  float*    Bqkv  = (float*)alloc(768 * 4);
  uint16_t* WTvec = (uint16_t*)alloc(384 * 128 * 2);
  uint16_t* WTdkv = (uint16_t*)alloc(512 * 64 * 2);
  float*    Bdkv  = (float*)alloc(512 * 4);
  uint16_t* WTo   = (uint16_t*)alloc(384 * 128 * 2);
  int*      deg   = (int*)alloc(NN * 4);
  int*      off   = (int*)alloc((NN + 1) * 4);
  int*      cur   = (int*)alloc(NN * 4);
  int*      bsum  = (int*)alloc(256 * 4);
  int*      perm  = (int*)alloc((size_t)NE * 4);
  int*      sndp  = (int*)alloc((size_t)NE * 4);
  int*      rcvp  = (int*)alloc((size_t)NE * 4);
  float4*   edata = (float4*)alloc((size_t)NE * 16);
  uint16_t* ea_perm = (uint16_t*)alloc((size_t)NE * 64 * 2);
  uint16_t* xn_b  = (uint16_t*)alloc((size_t)NN * 128 * 2);
  uint16_t* qkv_b = (uint16_t*)alloc((size_t)NN * 768 * 2);
  uint16_t* qk_b  = (uint16_t*)alloc((size_t)NN * 256 * 2);
  uint16_t* vec_b = (uint16_t*)alloc((size_t)NN * 3 * 128 * 2);
  uint16_t* vec_w = (uint16_t*)alloc((size_t)NN * 512 * 2);
  uint16_t* vp    = (uint16_t*)alloc((size_t)NN * 3 * 384 * 2);
  float*    o      = (float*)alloc((size_t)NN * 384 * 4);
  uint16_t* xagg_b = (uint16_t*)alloc((size_t)NN * 128 * 2);

  float* xagg   = (float*)d_out;
  float* vecagg = (float*)d_out + (size_t)NN * 128;

  hipMemsetAsync(d_out, 0, (size_t)out_size * 4, stream);

  // ---- weights prep (1 launch) ----
  k_prep<<<cdiv_i(98304 + 49152 + 32768 + 49152 + 1280, 256), 256, 0, stream>>>(
      Wq, Wk, Wv, Wvec, Wdk, Wdv, Wo, bq, bk, bv, bdk, bdv,
      WTqkv, WTvec, WTdkv, WTo, Bqkv, Bdkv);

  // ---- edge sort by receiver ----
  int NSB = cdiv_i(NN, 256);
  hipMemsetAsync(deg, 0, NN * 4, stream);
  k_hist<<<cdiv_i(NE, 256), 256, 0, stream>>>(rcv, deg);
  k_scan1<<<NSB, 256, 0, stream>>>(deg, bsum);
  k_scan2<<<1, 64, 0, stream>>>(bsum, NSB, off);
  k_scan3<<<NSB, 256, 0, stream>>>(deg, bsum, off, cur);
  k_scatter<<<cdiv_i(NE, 256), 256, 0, stream>>>(rcv, cur, perm);
  k_permute<<<cdiv_i((long long)NE * 16, 256), 256, 0, stream>>>(ea, perm, snd, rcv, ew, evec,
                                                                 ea_perm, sndp, rcvp, edata);

  // ---- node pre (1 launch: LN + vec GEMM-layout + vec walk-layout) ----
  k_node_pre<<<30000, 256, 0, stream>>>(x, ln_s, ln_b, vec, xn_b, vec_b, vec_w);

  // qkv = xn @ [Wq|Wk|Wv-interleaved] + b  (bf16 out, Fo=768)
  { dim3 g(768 / 128, cdiv_i(NN, 128));
    k_gemm<128, true, false><<<g, 256, 0, stream>>>(xn_b, WTqkv, Bqkv, qkv_b, NN, 768); }
  k_headln<<<cdiv_i((long long)NN * 16, 256), 256, 0, stream>>>(qkv_b, qln_s, qln_b, kln_s, kln_b, qk_b);

  // vp = vec @ Wvec (bf16 out)
  { dim3 g(384 / 128, cdiv_i((long long)NN * 3, 128));
    k_gemm<128, true, false><<<g, 256, 0, stream>>>(vec_b, WTvec, nullptr, vp, NN * 3, 384); }

  // ---- fully fused edge phase ----
  k_edge_all<<<NE / 64, 256, 0, stream>>>(ea_perm, sndp, rcvp, off, edata, WTdkv, Bdkv,
                                          qk_b, qkv_b, vec_w, xagg, vecagg);

  // o = x_agg @ Wo + bo
  k_cast_bf16<<<cdiv_i((long long)NN * 64, 256), 256, 0, stream>>>(xagg, xagg_b, NN * 64);
  { dim3 g(384 / 128, cdiv_i(NN, 128));
    k_gemm<128, false, false><<<g, 256, 0, stream>>>(xagg_b, WTo, bo, o, NN, 384); }

  // outputs
  k_final<<<cdiv_i((long long)NN * 128, 256), 256, 0, stream>>>(o, vp, xagg, vecagg);
}

// Round 14
// 342.614 us; speedup vs baseline: 1.0396x; 1.0227x over previous
//
#include <hip/hip_runtime.h>
#include <stdint.h>

#define NN 20000
#define NE 200000   // == 3125 * 64 exactly (k_edge_all assumes this)
// H=128, NH=8, HD=16, RBF=64

typedef __attribute__((ext_vector_type(8))) short bf16x8;
typedef __attribute__((ext_vector_type(4))) float f32x4;

__device__ __forceinline__ float bf2f(uint32_t u) {
  union { uint32_t i; float f; } v; v.i = u << 16; return v.f;
}
__device__ __forceinline__ uint16_t f2bf(float f) {
  union { float f; uint32_t i; } v; v.f = f;
  return (uint16_t)((v.i + 0x7fffu + ((v.i >> 16) & 1u)) >> 16);
}
__device__ __forceinline__ uint32_t pk2(float lo, float hi) {
  return (uint32_t)f2bf(lo) | ((uint32_t)f2bf(hi) << 16);
}
__device__ __forceinline__ float siluf(float x) { return x / (1.f + __expf(-x)); }
__device__ __forceinline__ float prod2(uint32_t q2, uint32_t k2, uint32_t d2) {
  return bf2f(q2 & 0xffffu) * bf2f(k2 & 0xffffu) * bf2f(d2 & 0xffffu)
       + bf2f(q2 >> 16) * bf2f(k2 >> 16) * bf2f(d2 >> 16);
}

// ---------------- consolidated weight prep (one launch) ----------------
// WTqkv [768][128]: rows 0-255 = q|k; rows 256-767 v INTERLEAVED
// (row 256 + j*4 + c, j=h*16+d, c=0..2 from orig col h*48+c*16+d, c==3 pad).
// WTdkv2 [512][64] column-reordered: dk | xm | m1 | m2.
__global__ void k_prep(const float* __restrict__ Wq, const float* __restrict__ Wk,
                       const float* __restrict__ Wv, const float* __restrict__ Wvec,
                       const float* __restrict__ Wdk, const float* __restrict__ Wdv,
                       const float* __restrict__ Wo, const float* __restrict__ bq,
                       const float* __restrict__ bk, const float* __restrict__ bv,
                       const float* __restrict__ bdk, const float* __restrict__ bdv,
                       uint16_t* __restrict__ WTqkv, uint16_t* __restrict__ WTvec,
                       uint16_t* __restrict__ WTdkv2, uint16_t* __restrict__ WTo,
                       float* __restrict__ Bqkv, float* __restrict__ Bdkv2) {
  int idx = blockIdx.x * 256 + threadIdx.x;
  if (idx < 98304) {                       // WTqkv [768][128]
    int rr = idx >> 7, k = idx & 127;
    float v;
    if (rr < 128)      v = Wq[k * 128 + rr];
    else if (rr < 256) v = Wk[k * 128 + rr - 128];
    else {
      int j2 = rr - 256, j = j2 >> 2, c = j2 & 3;
      v = (c < 3) ? Wv[k * 384 + (j >> 4) * 48 + c * 16 + (j & 15)] : 0.f;
    }
    WTqkv[idx] = f2bf(v);
    return;
  }
  idx -= 98304;
  if (idx < 49152) {                       // WTvec [384][128]
    int c = idx >> 7, k = idx & 127;
    WTvec[idx] = f2bf(Wvec[k * 384 + c]);
    return;
  }
  idx -= 49152;
  if (idx < 32768) {                       // WTdkv2 [512][64], reordered
    int rr = idx >> 6, k = idx & 63;
    float v;
    if (rr < 128) v = Wdk[k * 128 + rr];
    else {
      int j = rr - 128, p = j >> 7, hd = j & 127;
      v = Wdv[k * 384 + (hd >> 4) * 48 + p * 16 + (hd & 15)];
    }
    WTdkv2[idx] = f2bf(v);
    return;
  }
  idx -= 32768;
  if (idx < 49152) {                       // WTo [384][128]
    int c = idx >> 7, k = idx & 127;
    WTo[idx] = f2bf(Wo[k * 384 + c]);
    return;
  }
  idx -= 49152;
  if (idx < 768) {                         // Bqkv [768]
    if (idx < 128)      Bqkv[idx] = bq[idx];
    else if (idx < 256) Bqkv[idx] = bk[idx - 128];
    else {
      int j2 = idx - 256, j = j2 >> 2, c = j2 & 3;
      Bqkv[idx] = (c < 3) ? bv[(j >> 4) * 48 + c * 16 + (j & 15)] : 0.f;
    }
  } else if (idx < 1280) {
    int t = idx - 768;
    if (t < 128) Bdkv2[t] = bdk[t];
    else {
      int j = t - 128, p = j >> 7, hd = j & 127;
      Bdkv2[t] = bdv[(hd >> 4) * 48 + p * 16 + (hd & 15)];
    }
  }
}

// ---------------- node pre: LN(x)->bf16 + vec walk-slots of combo (12B rows) ----------------
__global__ void k_node_pre(const float* __restrict__ x, const float* __restrict__ s,
                           const float* __restrict__ b, const float* __restrict__ vec,
                           uint16_t* __restrict__ xn_b, uint16_t* __restrict__ combo) {
  if (blockIdx.x < 5000) {
    int gt = blockIdx.x * 256 + threadIdx.x;
    int node = gt >> 6, lane = gt & 63;
    if (node >= NN) return;
    const float* row = x + (size_t)node * 128;
    float2 v = *(const float2*)&row[lane * 2];
    float sum = v.x + v.y, sq = v.x * v.x + v.y * v.y;
    #pragma unroll
    for (int off = 32; off; off >>= 1) { sum += __shfl_xor(sum, off); sq += __shfl_xor(sq, off); }
    float mu = sum * (1.f / 128.f);
    float var = sq * (1.f / 128.f) - mu * mu;
    float rs = rsqrtf(var + 1e-6f);
    float o0 = (v.x - mu) * rs * s[lane * 2] + b[lane * 2];
    float o1 = (v.y - mu) * rs * s[lane * 2 + 1] + b[lane * 2 + 1];
    ((uint32_t*)xn_b)[(size_t)node * 64 + lane] = pk2(o0, o1);
  } else {
    int i = (blockIdx.x - 5000) * 256 + threadIdx.x;  // NN*128 triples
    if (i >= NN * 128) return;
    int n = i >> 7, j = i & 127;
    const float* vr = vec + (size_t)n * 384 + j;
    uint16_t* cb = &combo[(size_t)n * 768 + j * 6];
    cb[3] = f2bf(vr[0]);                          // w0
    *(uint32_t*)&cb[4] = pk2(vr[128], vr[256]);   // w1|w2 (4B aligned)
  }
}

// ---------------- edge sort by receiver (counting sort, parallel scan) ----------------
__global__ void k_hist(const int* __restrict__ rcv, int* __restrict__ deg) {
  int e = blockIdx.x * 256 + threadIdx.x;
  if (e < NE) atomicAdd(&deg[rcv[e]], 1);
}

__global__ void k_scan1(const int* __restrict__ deg, int* __restrict__ bsum) {
  __shared__ int ws[4];
  int i = blockIdx.x * 256 + threadIdx.x;
  int x = (i < NN) ? deg[i] : 0;
  #pragma unroll
  for (int d = 32; d; d >>= 1) x += __shfl_xor(x, d);
  if ((threadIdx.x & 63) == 0) ws[threadIdx.x >> 6] = x;
  __syncthreads();
  if (threadIdx.x == 0) bsum[blockIdx.x] = ws[0] + ws[1] + ws[2] + ws[3];
}

__global__ void k_scan2(int* __restrict__ bsum, int nb, int* __restrict__ off) {
  int lane = threadIdx.x;
  int carry = 0;
  for (int base = 0; base < nb; base += 64) {
    int i = base + lane;
    int x = (i < nb) ? bsum[i] : 0;
    int v = x;
    #pragma unroll
    for (int d = 1; d < 64; d <<= 1) { int y = __shfl_up(v, d); if (lane >= d) v += y; }
    if (i < nb) bsum[i] = carry + v - x;
    carry += __shfl(v, 63);
  }
  if (lane == 0) off[NN] = carry;
}

__global__ void k_scan3(const int* __restrict__ deg, const int* __restrict__ bsum,
                        int* __restrict__ off, int* __restrict__ cur) {
  __shared__ int ws[4];
  int t = threadIdx.x, lane = t & 63, w = t >> 6;
  int i = blockIdx.x * 256 + t;
  int x = (i < NN) ? deg[i] : 0;
  int v = x;
  #pragma unroll
  for (int d = 1; d < 64; d <<= 1) { int y = __shfl_up(v, d); if (lane >= d) v += y; }
  if (lane == 63) ws[w] = v;
  __syncthreads();
  int wadd = 0;
  for (int j = 0; j < w; j++) wadd += ws[j];
  int excl = bsum[blockIdx.x] + wadd + v - x;
  if (i < NN) { off[i] = excl; cur[i] = excl; }
}

__global__ void k_scatter(const int* __restrict__ rcv, int* __restrict__ cur,
                          int* __restrict__ perm) {
  int e = blockIdx.x * 256 + threadIdx.x;
  if (e >= NE) return;
  int pos = atomicAdd(&cur[rcv[e]], 1);
  perm[pos] = e;
}

// gather+cast edge_attr rows in permuted order; also permute snd/rcv and
// pack (evec.xyz, cutoff(ew)) into edata
__global__ void k_permute(const float* __restrict__ ea, const int* __restrict__ perm,
                          const int* __restrict__ snd, const int* __restrict__ rcv,
                          const float* __restrict__ ew, const float* __restrict__ evec,
                          uint16_t* __restrict__ ea_perm, int* __restrict__ sndp,
                          int* __restrict__ rcvp, float4* __restrict__ edata) {
  int idx = blockIdx.x * 256 + threadIdx.x;   // 16 threads per edge
  if (idx >= NE * 16) return;
  int i = idx >> 4, j = idx & 15;
  int e = perm[i];
  float4 v = *(const float4*)&ea[(size_t)e * 64 + j * 4];
  uint2 o;
  o.x = pk2(v.x, v.y);
  o.y = pk2(v.z, v.w);
  *(uint2*)&ea_perm[(size_t)i * 64 + j * 4] = o;
  if (j == 0) {
    sndp[i] = snd[e];
    rcvp[i] = rcv[e];
    float w = ew[e];
    float cut = (w < 5.f) ? 0.5f * (__cosf(w * 0.628318530717958648f) + 1.f) : 0.f;
    edata[i] = make_float4(evec[e * 3], evec[e * 3 + 1], evec[e * 3 + 2], cut);
  }
}

// ---------------- bf16 MFMA GEMM: C = act(A @ BT^T + bias) ----------------
// AF32: A is f32, cast to bf16 during LDS staging.
template <int KTOT, bool OUT_BF16, bool SILU, bool AF32>
__global__ __launch_bounds__(256) void k_gemm(const void* __restrict__ A,
                                              const uint16_t* __restrict__ BT,
                                              const float* __restrict__ bias,
                                              void* __restrict__ Cout, int M, int Fo) {
  __shared__ __align__(16) uint16_t As[128 * 72];
  __shared__ __align__(16) uint16_t Bs[128 * 72];
  const uint16_t* A16 = (const uint16_t*)A;
  const float* A32 = (const float*)A;
  int t = threadIdx.x;
  int l = t & 63;
  int row0 = blockIdx.y * 128, col0 = blockIdx.x * 128;
  int wm = ((t >> 6) >> 1) * 64, wn = ((t >> 6) & 1) * 64;
  f32x4 acc[4][4] = {};
  for (int kt = 0; kt < KTOT; kt += 64) {
    __syncthreads();
    #pragma unroll
    for (int i = 0; i < 4; i++) {
      int c = i * 256 + t;
      int row = c >> 3, ko = (c & 7) * 8;
      uint4 av = make_uint4(0u, 0u, 0u, 0u);
      int gr = row0 + row;
      if (gr < M) {
        if (AF32) {
          float4 f0 = *(const float4*)&A32[(size_t)gr * KTOT + kt + ko];
          float4 f1 = *(const float4*)&A32[(size_t)gr * KTOT + kt + ko + 4];
          av = make_uint4(pk2(f0.x, f0.y), pk2(f0.z, f0.w), pk2(f1.x, f1.y), pk2(f1.z, f1.w));
        } else {
          av = *(const uint4*)&A16[(size_t)gr * KTOT + kt + ko];
        }
      }
      *(uint4*)&As[row * 72 + ko] = av;
      uint4 bw = *(const uint4*)&BT[(size_t)(col0 + row) * KTOT + kt + ko];
      *(uint4*)&Bs[row * 72 + ko] = bw;
    }
    __syncthreads();
    #pragma unroll
    for (int kk = 0; kk < 64; kk += 32) {
      bf16x8 af[4], bfr[4];
      #pragma unroll
      for (int mf = 0; mf < 4; mf++)
        af[mf] = *(const bf16x8*)&As[(wm + mf * 16 + (l & 15)) * 72 + (l >> 4) * 8 + kk];
      #pragma unroll
      for (int nf = 0; nf < 4; nf++)
        bfr[nf] = *(const bf16x8*)&Bs[(wn + nf * 16 + (l & 15)) * 72 + (l >> 4) * 8 + kk];
      #pragma unroll
      for (int mf = 0; mf < 4; mf++)
        #pragma unroll
        for (int nf = 0; nf < 4; nf++)
          acc[mf][nf] = __builtin_amdgcn_mfma_f32_16x16x32_bf16(af[mf], bfr[nf], acc[mf][nf], 0, 0, 0);
    }
  }
  float* Cf = (float*)Cout;
  uint16_t* Cb = (uint16_t*)Cout;
  #pragma unroll
  for (int mf = 0; mf < 4; mf++) {
    #pragma unroll
    for (int r = 0; r < 4; r++) {
      int grow = row0 + wm + mf * 16 + (l >> 4) * 4 + r;
      if (grow >= M) continue;
      #pragma unroll
      for (int nf = 0; nf < 4; nf++) {
        int gcol = col0 + wn + nf * 16 + (l & 15);
        float v = acc[mf][nf][r];
        if (bias) v += bias[gcol];
        if (SILU) v = siluf(v);
        if (OUT_BF16) Cb[(size_t)grow * Fo + gcol] = f2bf(v);
        else          Cf[(size_t)grow * Fo + gcol] = v;
      }
    }
  }
}

// ---------------- qkv GEMM: plain epilogue; q/k -> qk_raw [NN,256], v -> combo slots ----------------
__global__ __launch_bounds__(256) void k_gemm_qkv2(
    const uint16_t* __restrict__ A, const uint16_t* __restrict__ BT,
    const float* __restrict__ bias, uint16_t* __restrict__ qk_raw,
    uint16_t* __restrict__ combo) {
  __shared__ __align__(16) uint16_t As[128 * 72];
  __shared__ __align__(16) uint16_t Bs[128 * 72];
  int t = threadIdx.x;
  int l = t & 63;
  int row0 = blockIdx.y * 128, col0 = blockIdx.x * 128;
  int wm = ((t >> 6) >> 1) * 64, wn = ((t >> 6) & 1) * 64;
  f32x4 acc[4][4] = {};
  for (int kt = 0; kt < 128; kt += 64) {
    __syncthreads();
    #pragma unroll
    for (int i = 0; i < 4; i++) {
      int c = i * 256 + t;
      int row = c >> 3, ko = (c & 7) * 8;
      uint4 av = make_uint4(0u, 0u, 0u, 0u);
      int gr = row0 + row;
      if (gr < NN) av = *(const uint4*)&A[(size_t)gr * 128 + kt + ko];
      *(uint4*)&As[row * 72 + ko] = av;
      uint4 bw = *(const uint4*)&BT[(size_t)(col0 + row) * 128 + kt + ko];
      *(uint4*)&Bs[row * 72 + ko] = bw;
    }
    __syncthreads();
    #pragma unroll
    for (int kk = 0; kk < 64; kk += 32) {
      bf16x8 af[4], bfr[4];
      #pragma unroll
      for (int mf = 0; mf < 4; mf++)
        af[mf] = *(const bf16x8*)&As[(wm + mf * 16 + (l & 15)) * 72 + (l >> 4) * 8 + kk];
      #pragma unroll
      for (int nf = 0; nf < 4; nf++)
        bfr[nf] = *(const bf16x8*)&Bs[(wn + nf * 16 + (l & 15)) * 72 + (l >> 4) * 8 + kk];
      #pragma unroll
      for (int mf = 0; mf < 4; mf++)
        #pragma unroll
        for (int nf = 0; nf < 4; nf++)
          acc[mf][nf] = __builtin_amdgcn_mfma_f32_16x16x32_bf16(af[mf], bfr[nf], acc[mf][nf], 0, 0, 0);
    }
  }
  int d = l & 15;
  #pragma unroll
  for (int mf = 0; mf < 4; mf++) {
    #pragma unroll
    for (int r = 0; r < 4; r++) {
      int grow = row0 + wm + mf * 16 + (l >> 4) * 4 + r;
      if (grow >= NN) continue;
      #pragma unroll
      for (int nf = 0; nf < 4; nf++) {
        int gcol = col0 + wn + nf * 16 + d;
        float v = acc[mf][nf][r] + bias[gcol];
        if (col0 < 256) {
          qk_raw[(size_t)grow * 256 + gcol] = f2bf(v);
        } else {
          int j2 = gcol - 256, j = j2 >> 2, c = j2 & 3;
          if (c < 3) combo[(size_t)grow * 768 + j * 6 + c] = f2bf(v);
        }
      }
    }
  }
}

// ---------------- per-head LN on q/k (bf16 in/out, qk_raw stride 256) ----------------
__global__ void k_headln(const uint16_t* __restrict__ qkv, const float* __restrict__ qs,
                         const float* __restrict__ qb, const float* __restrict__ ks,
                         const float* __restrict__ kb, uint16_t* __restrict__ out) {
  int idx = blockIdx.x * 256 + threadIdx.x;
  if (idx >= NN * 16) return;
  int n = idx >> 4, ph = idx & 15, part = ph >> 3, h = ph & 7;
  const uint16_t* src = qkv + (size_t)n * 256 + part * 128 + h * 16;
  float v[16], sum = 0.f;
  #pragma unroll
  for (int i = 0; i < 16; i++) { v[i] = bf2f(src[i]); sum += v[i]; }
  float mu = sum * (1.f / 16.f), var = 0.f;
  #pragma unroll
  for (int i = 0; i < 16; i++) { float dd = v[i] - mu; var += dd * dd; }
  float rs = rsqrtf(var * (1.f / 16.f) + 1e-6f);
  const float* sc = part ? ks : qs;
  const float* bb = part ? kb : qb;
  uint16_t* dst = out + (size_t)n * 256 + part * 128 + h * 16;
  #pragma unroll
  for (int i = 0; i < 16; i++) dst[i] = f2bf((v[i] - mu) * rs * sc[i] + bb[i]);
}

// ---------------- FULLY FUSED edge phase (combo 12B walk + dk plane) ----------------
#define MTS 516   // walk-tile row stride (shorts): slots 0=xm 1=m1 2=m2, 3 pad

__device__ __forceinline__ void mfma32(const uint16_t* As, int r0,
                                       const uint16_t* __restrict__ BT2, int cb,
                                       int wn, int l, f32x4 acc[2][2]) {
  #pragma unroll
  for (int kk = 0; kk < 2; kk++) {
    bf16x8 af[2];
    #pragma unroll
    for (int mf = 0; mf < 2; mf++)
      af[mf] = *(const bf16x8*)&As[(r0 + mf * 16 + (l & 15)) * 68 + (l >> 4) * 8 + kk * 32];
    #pragma unroll
    for (int nf = 0; nf < 2; nf++) {
      bf16x8 bv = *(const bf16x8*)&BT2[(size_t)(cb * 128 + wn + nf * 16 + (l & 15)) * 64 +
                                       (l >> 4) * 8 + kk * 32];
      #pragma unroll
      for (int mf = 0; mf < 2; mf++)
        acc[mf][nf] = __builtin_amdgcn_mfma_f32_16x16x32_bf16(af[mf], bv, acc[mf][nf], 0, 0, 0);
    }
  }
}

__device__ __forceinline__ void silu_slot(uint16_t* mt, const float bsv[2], int slot,
                                          int wn, int l, f32x4 acc[2][2]) {
  #pragma unroll
  for (int mf = 0; mf < 2; mf++)
    #pragma unroll
    for (int r = 0; r < 4; r++) {
      int row = mf * 16 + (l >> 4) * 4 + r;
      #pragma unroll
      for (int nf = 0; nf < 2; nf++) {
        int c = wn + nf * 16 + (l & 15);
        mt[row * MTS + c * 4 + slot] = f2bf(siluf(acc[mf][nf][r] + bsv[nf]));
      }
    }
}

__device__ __forceinline__ void silu_dk(uint16_t* mtd, const float bsv[2],
                                        int wn, int l, f32x4 acc[2][2]) {
  #pragma unroll
  for (int mf = 0; mf < 2; mf++)
    #pragma unroll
    for (int r = 0; r < 4; r++) {
      int row = mf * 16 + (l >> 4) * 4 + r;
      #pragma unroll
      for (int nf = 0; nf < 2; nf++) {
        int c = wn + nf * 16 + (l & 15);
        mtd[row * 140 + c] = f2bf(siluf(acc[mf][nf][r] + bsv[nf]));
      }
    }
}

__global__ __launch_bounds__(256) void k_edge_all(
    const uint16_t* __restrict__ eap, const int* __restrict__ sndp,
    const int* __restrict__ rcvp, const int* __restrict__ off,
    const float4* __restrict__ edata, const uint16_t* __restrict__ WT2,
    const float* __restrict__ Bd2, const uint16_t* __restrict__ qk_b,
    const uint16_t* __restrict__ combo, float* __restrict__ xagg,
    float* __restrict__ vecagg) {
  __shared__ __align__(16) uint16_t As[64 * 68];     // 8.7 KB
  __shared__ __align__(16) uint16_t mt[32 * MTS];    // 33 KB (xm,m1,m2 slots)
  __shared__ __align__(16) uint16_t mtd[32 * 140];   // 8.96 KB (dk)
  __shared__ float attn_l[32 * 8];                   // 1 KB
  __shared__ int sndl[64], rcvl[64], lo_g[64], hi_g[64];
  __shared__ float4 ed4[64];

  int e0 = blockIdx.x * 64;
  int t = threadIdx.x, l = t & 63, wn = (t >> 6) * 32;

  // ---- meta + A stage + bias regs ----
  if (t < 64) {
    int e = e0 + t;
    int r = rcvp[e];
    sndl[t] = sndp[e]; rcvl[t] = r;
    lo_g[t] = off[r]; hi_g[t] = off[r + 1];
    ed4[t] = edata[e];
  }
  #pragma unroll
  for (int i = 0; i < 2; i++) {
    int c = i * 256 + t;
    int row = c >> 3, ko = (c & 7) * 8;
    *(uint4*)&As[row * 68 + ko] = *(const uint4*)&eap[(size_t)(e0 + row) * 64 + ko];
  }
  float bs[4][2];
  #pragma unroll
  for (int cb = 0; cb < 4; cb++) {
    bs[cb][0] = Bd2[cb * 128 + wn + (l & 15)];
    bs[cb][1] = Bd2[cb * 128 + wn + 16 + (l & 15)];
  }
  __syncthreads();

  #pragma unroll
  for (int half = 0; half < 2; half++) {
    int r0 = half * 32;
    // ---- P1: cb0 dk -> mtd ----
    { f32x4 acc[2][2] = {}; mfma32(As, r0, WT2, 0, wn, l, acc); silu_dk(mtd, bs[0], wn, l, acc); }
    __syncthreads();
    // ---- P2: q/k loads early, cb1-3 MFMA hide them, then attn dot ----
    {
      int el = t >> 3, h = t & 7;
      int ge = r0 + el;
      int rn = rcvl[ge], sn = sndl[ge];
      const uint16_t* qb_ = qk_b + (size_t)rn * 256 + h * 16;
      const uint16_t* kb_ = qk_b + (size_t)sn * 256 + 128 + h * 16;
      uint4 q0 = *(const uint4*)qb_;
      uint4 q1 = *(const uint4*)(qb_ + 8);
      uint4 k0 = *(const uint4*)kb_;
      uint4 k1 = *(const uint4*)(kb_ + 8);
      { f32x4 acc[2][2] = {}; mfma32(As, r0, WT2, 1, wn, l, acc); silu_slot(mt, bs[1], 0, wn, l, acc); }
      { f32x4 acc[2][2] = {}; mfma32(As, r0, WT2, 2, wn, l, acc); silu_slot(mt, bs[2], 1, wn, l, acc); }
      { f32x4 acc[2][2] = {}; mfma32(As, r0, WT2, 3, wn, l, acc); silu_slot(mt, bs[3], 2, wn, l, acc); }
      const uint32_t* dp = (const uint32_t*)&mtd[el * 140 + h * 16];
      uint32_t qa[8] = {q0.x, q0.y, q0.z, q0.w, q1.x, q1.y, q1.z, q1.w};
      uint32_t ka[8] = {k0.x, k0.y, k0.z, k0.w, k1.x, k1.y, k1.z, k1.w};
      float dot = 0.f;
      #pragma unroll
      for (int j = 0; j < 8; j++) dot += prod2(qa[j], ka[j], dp[j]);
      attn_l[el * 8 + h] = siluf(dot) * ed4[ge].w;
    }
    __syncthreads();
    // ---- P3: merged walk; 12B combo gather per (edge,col) ----
    {
      int col = t & 127, sub = t >> 7;
      int i0 = r0 + sub * 16, i1 = i0 + 16;
      int ha = col >> 4;
      float accx = 0.f, a0 = 0.f, a1 = 0.f, a2 = 0.f;
      #pragma unroll 8
      for (int i = i0; i < i1; i++) {
        int li = i - r0;
        int n = rcvl[i], s = sndl[i];
        const uint16_t* cp = &combo[(size_t)s * 768 + col * 6];
        uint32_t u0 = *(const uint32_t*)cp;        // v0|v1
        uint32_t u1 = *(const uint32_t*)(cp + 2);  // v2|w0
        uint32_t u2 = *(const uint32_t*)(cp + 4);  // w1|w2
        uint2 mr = *(const uint2*)&mt[li * MTS + col * 4];
        float a = attn_l[li * 8 + ha];
        float xmv = bf2f(mr.x & 0xffffu), m1v = bf2f(mr.x >> 16), m2v = bf2f(mr.y & 0xffffu);
        accx += bf2f(u0 & 0xffffu) * xmv * a;
        float mm1 = bf2f(u0 >> 16) * m1v;
        float mm2 = bf2f(u1 & 0xffffu) * m2v;
        float4 ev = ed4[i];
        a0 += bf2f(u1 >> 16)     * mm1 + ev.x * mm2;
        a1 += bf2f(u2 & 0xffffu) * mm1 + ev.y * mm2;
        a2 += bf2f(u2 >> 16)     * mm1 + ev.z * mm2;
        if (i == i1 - 1 || rcvl[i + 1] != n) {
          bool cont = (lo_g[i] >= e0 + i0) && (hi_g[i] <= e0 + i1);
          float* dx_ = &xagg[(size_t)n * 128 + col];
          float* d0 = &vecagg[((size_t)n * 3 + 0) * 128 + col];
          float* d1 = &vecagg[((size_t)n * 3 + 1) * 128 + col];
          float* d2 = &vecagg[((size_t)n * 3 + 2) * 128 + col];
          if (cont) { *dx_ = accx; *d0 = a0; *d1 = a1; *d2 = a2; }
          else { atomicAdd(dx_, accx); atomicAdd(d0, a0); atomicAdd(d1, a1); atomicAdd(d2, a2); }
          accx = a0 = a1 = a2 = 0.f;
        }
      }
    }
    __syncthreads();
  }
}

// ---------------- final ----------------
__global__ void k_final(const float* __restrict__ o, const uint16_t* __restrict__ vp,
                        float* __restrict__ dx, float* __restrict__ dvec) {
  int idx = blockIdx.x * 256 + threadIdx.x;
  if (idx >= NN * 128) return;
  int n = idx >> 7, j = idx & 127;
  const float* op = o + (size_t)n * 384;
  float o1 = op[j], o2 = op[128 + j], o3 = op[256 + j];
  const uint16_t* vpn = vp + (size_t)n * 3 * 384;
  float vd = 0.f;
  #pragma unroll
  for (int c = 0; c < 3; c++)
    vd += bf2f(vpn[c * 384 + j]) * bf2f(vpn[c * 384 + 128 + j]);
  dx[idx] = vd * o2 + o3;
  #pragma unroll
  for (int c = 0; c < 3; c++) {
    size_t vi = ((size_t)n * 3 + c) * 128 + j;
    dvec[vi] = bf2f(vpn[c * 384 + 256 + j]) * o1 + dvec[vi];
  }
}

static inline int cdiv_i(long long a, long long b) { return (int)((a + b - 1) / b); }

extern "C" void kernel_launch(void* const* d_in, const int* in_sizes, int n_in,
                              void* d_out, int out_size, void* d_ws, size_t ws_size,
                              hipStream_t stream) {
  const float* x    = (const float*)d_in[0];
  const float* vec  = (const float*)d_in[1];
  const float* ew   = (const float*)d_in[2];
  const float* ea   = (const float*)d_in[3];
  const float* evec = (const float*)d_in[4];
  const int*   snd  = (const int*)d_in[5];
  const int*   rcv  = (const int*)d_in[6];
  const float* ln_s = (const float*)d_in[7];
  const float* ln_b = (const float*)d_in[8];
  const float* Wq = (const float*)d_in[9];   const float* bq = (const float*)d_in[10];
  const float* Wk = (const float*)d_in[11];  const float* bk = (const float*)d_in[12];
  const float* Wv = (const float*)d_in[13];  const float* bv = (const float*)d_in[14];
  const float* Wvec = (const float*)d_in[15];
  const float* Wdk = (const float*)d_in[16]; const float* bdk = (const float*)d_in[17];
  const float* Wdv = (const float*)d_in[18]; const float* bdv = (const float*)d_in[19];
  const float* Wo = (const float*)d_in[20];  const float* bo = (const float*)d_in[21];
  const float* qln_s = (const float*)d_in[22]; const float* qln_b = (const float*)d_in[23];
  const float* kln_s = (const float*)d_in[24]; const float* kln_b = (const float*)d_in[25];
  (void)in_sizes; (void)n_in; (void)ws_size;

  uint8_t* p = (uint8_t*)d_ws;
  auto alloc = [&](size_t bytes) -> uint8_t* {
    uint8_t* r = p; p += (bytes + 255) & ~(size_t)255; return r;
  };
  uint16_t* WTqkv = (uint16_t*)alloc(768 * 128 * 2);
  float*    Bqkv  = (float*)alloc(768 * 4);
  uint16_t* WTvec = (uint16_t*)alloc(384 * 128 * 2);
  uint16_t* WTdkv = (uint16_t*)alloc(512 * 64 * 2);
  float*    Bdkv  = (float*)alloc(512 * 4);
  uint16_t* WTo   = (uint16_t*)alloc(384 * 128 * 2);
  int*      deg   = (int*)alloc(NN * 4);
  int*      off   = (int*)alloc((NN + 1) * 4);
  int*      cur   = (int*)alloc(NN * 4);
  int*      bsum  = (int*)alloc(256 * 4);
  int*      perm  = (int*)alloc((size_t)NE * 4);
  int*      sndp  = (int*)alloc((size_t)NE * 4);
  int*      rcvp  = (int*)alloc((size_t)NE * 4);
  float4*   edata = (float4*)alloc((size_t)NE * 16);
  uint16_t* ea_perm = (uint16_t*)alloc((size_t)NE * 64 * 2);
  uint16_t* xn_b  = (uint16_t*)alloc((size_t)NN * 128 * 2);
  uint16_t* qk_raw = (uint16_t*)alloc((size_t)NN * 256 * 2);
  uint16_t* qk_b  = (uint16_t*)alloc((size_t)NN * 256 * 2);
  uint16_t* combo = (uint16_t*)alloc((size_t)NN * 768 * 2);
  uint16_t* vp    = (uint16_t*)alloc((size_t)NN * 3 * 384 * 2);
  float*    o     = (float*)alloc((size_t)NN * 384 * 4);

  float* xagg   = (float*)d_out;
  float* vecagg = (float*)d_out + (size_t)NN * 128;

  hipMemsetAsync(d_out, 0, (size_t)out_size * 4, stream);

  // ---- weights prep (1 launch) ----
  k_prep<<<cdiv_i(98304 + 49152 + 32768 + 49152 + 1280, 256), 256, 0, stream>>>(
      Wq, Wk, Wv, Wvec, Wdk, Wdv, Wo, bq, bk, bv, bdk, bdv,
      WTqkv, WTvec, WTdkv, WTo, Bqkv, Bdkv);

  // ---- edge sort by receiver ----
  int NSB = cdiv_i(NN, 256);
  hipMemsetAsync(deg, 0, NN * 4, stream);
  k_hist<<<cdiv_i(NE, 256), 256, 0, stream>>>(rcv, deg);
  k_scan1<<<NSB, 256, 0, stream>>>(deg, bsum);
  k_scan2<<<1, 64, 0, stream>>>(bsum, NSB, off);
  k_scan3<<<NSB, 256, 0, stream>>>(deg, bsum, off, cur);
  k_scatter<<<cdiv_i(NE, 256), 256, 0, stream>>>(rcv, cur, perm);
  k_permute<<<cdiv_i((long long)NE * 16, 256), 256, 0, stream>>>(ea, perm, snd, rcv, ew, evec,
                                                                 ea_perm, sndp, rcvp, edata);

  // ---- node pre (LN + combo w-slots) ----
  k_node_pre<<<5000 + cdiv_i((long long)NN * 128, 256), 256, 0, stream>>>(
      x, ln_s, ln_b, vec, xn_b, combo);

  // qkv GEMM: q/k plain -> qk_raw; v -> combo slots 0-2
  { dim3 g(6, cdiv_i(NN, 128));
    k_gemm_qkv2<<<g, 256, 0, stream>>>(xn_b, WTqkv, Bqkv, qk_raw, combo); }
  k_headln<<<cdiv_i((long long)NN * 16, 256), 256, 0, stream>>>(qk_raw, qln_s, qln_b,
                                                               kln_s, kln_b, qk_b);

  // vp = vec @ Wvec (f32 A staged to bf16; bf16 out)
  { dim3 g(384 / 128, cdiv_i((long long)NN * 3, 128));
    k_gemm<128, true, false, true><<<g, 256, 0, stream>>>(vec, WTvec, nullptr, vp, NN * 3, 384); }

  // ---- fully fused edge phase ----
  k_edge_all<<<NE / 64, 256, 0, stream>>>(ea_perm, sndp, rcvp, off, edata, WTdkv, Bdkv,
                                          qk_b, combo, xagg, vecagg);

  // o = x_agg @ Wo + bo (f32 A staged to bf16; f32 out)
  { dim3 g(384 / 128, cdiv_i(NN, 128));
    k_gemm<128, false, false, true><<<g, 256, 0, stream>>>(xagg, WTo, bo, o, NN, 384); }

  // outputs
  k_final<<<cdiv_i((long long)NN * 128, 256), 256, 0, stream>>>(o, vp, xagg, vecagg);
}

// Round 15
// 337.994 us; speedup vs baseline: 1.0538x; 1.0137x over previous
//
#include <hip/hip_runtime.h>
#include <stdint.h>

#define NN 20000
#define NE 200000   // == 3125 * 64 exactly (k_edge_all assumes this)
// H=128, NH=8, HD=16, RBF=64

typedef __attribute__((ext_vector_type(8))) short bf16x8;
typedef __attribute__((ext_vector_type(4))) float f32x4;

__device__ __forceinline__ float bf2f(uint32_t u) {
  union { uint32_t i; float f; } v; v.i = u << 16; return v.f;
}
__device__ __forceinline__ uint16_t f2bf(float f) {
  union { float f; uint32_t i; } v; v.f = f;
  return (uint16_t)((v.i + 0x7fffu + ((v.i >> 16) & 1u)) >> 16);
}
__device__ __forceinline__ uint32_t pk2(float lo, float hi) {
  return (uint32_t)f2bf(lo) | ((uint32_t)f2bf(hi) << 16);
}
__device__ __forceinline__ float siluf(float x) { return x / (1.f + __expf(-x)); }
__device__ __forceinline__ float prod2(uint32_t q2, uint32_t k2, uint32_t d2) {
  return bf2f(q2 & 0xffffu) * bf2f(k2 & 0xffffu) * bf2f(d2 & 0xffffu)
       + bf2f(q2 >> 16) * bf2f(k2 >> 16) * bf2f(d2 >> 16);
}

// ---------------- consolidated weight prep (one launch) ----------------
// WTqkv [768][128]: rows 0-255 = q|k; rows 256-767 v INTERLEAVED
// (row 256 + j*4 + c, j=h*16+d, c=0..2 from orig col h*48+c*16+d, c==3 pad).
// WTdkv2 [512][64] column-reordered: dk | xm | m1 | m2.
__global__ void k_prep(const float* __restrict__ Wq, const float* __restrict__ Wk,
                       const float* __restrict__ Wv, const float* __restrict__ Wvec,
                       const float* __restrict__ Wdk, const float* __restrict__ Wdv,
                       const float* __restrict__ Wo, const float* __restrict__ bq,
                       const float* __restrict__ bk, const float* __restrict__ bv,
                       const float* __restrict__ bdk, const float* __restrict__ bdv,
                       uint16_t* __restrict__ WTqkv, uint16_t* __restrict__ WTvec,
                       uint16_t* __restrict__ WTdkv2, uint16_t* __restrict__ WTo,
                       float* __restrict__ Bqkv, float* __restrict__ Bdkv2) {
  int idx = blockIdx.x * 256 + threadIdx.x;
  if (idx < 98304) {                       // WTqkv [768][128]
    int rr = idx >> 7, k = idx & 127;
    float v;
    if (rr < 128)      v = Wq[k * 128 + rr];
    else if (rr < 256) v = Wk[k * 128 + rr - 128];
    else {
      int j2 = rr - 256, j = j2 >> 2, c = j2 & 3;
      v = (c < 3) ? Wv[k * 384 + (j >> 4) * 48 + c * 16 + (j & 15)] : 0.f;
    }
    WTqkv[idx] = f2bf(v);
    return;
  }
  idx -= 98304;
  if (idx < 49152) {                       // WTvec [384][128]
    int c = idx >> 7, k = idx & 127;
    WTvec[idx] = f2bf(Wvec[k * 384 + c]);
    return;
  }
  idx -= 49152;
  if (idx < 32768) {                       // WTdkv2 [512][64], reordered
    int rr = idx >> 6, k = idx & 63;
    float v;
    if (rr < 128) v = Wdk[k * 128 + rr];
    else {
      int j = rr - 128, p = j >> 7, hd = j & 127;
      v = Wdv[k * 384 + (hd >> 4) * 48 + p * 16 + (hd & 15)];
    }
    WTdkv2[idx] = f2bf(v);
    return;
  }
  idx -= 32768;
  if (idx < 49152) {                       // WTo [384][128]
    int c = idx >> 7, k = idx & 127;
    WTo[idx] = f2bf(Wo[k * 384 + c]);
    return;
  }
  idx -= 49152;
  if (idx < 768) {                         // Bqkv [768]
    if (idx < 128)      Bqkv[idx] = bq[idx];
    else if (idx < 256) Bqkv[idx] = bk[idx - 128];
    else {
      int j2 = idx - 256, j = j2 >> 2, c = j2 & 3;
      Bqkv[idx] = (c < 3) ? bv[(j >> 4) * 48 + c * 16 + (j & 15)] : 0.f;
    }
  } else if (idx < 1280) {
    int t = idx - 768;
    if (t < 128) Bdkv2[t] = bdk[t];
    else {
      int j = t - 128, p = j >> 7, hd = j & 127;
      Bdkv2[t] = bdv[(hd >> 4) * 48 + p * 16 + (hd & 15)];
    }
  }
}

// ---------------- node pre: LN(x)->bf16 + vec walk-slots of combo + zero d_out ----------------
__global__ void k_node_pre(const float* __restrict__ x, const float* __restrict__ s,
                           const float* __restrict__ b, const float* __restrict__ vec,
                           uint16_t* __restrict__ xn_b, uint16_t* __restrict__ combo,
                           float4* __restrict__ dz) {
  if (blockIdx.x < 5000) {
    int gt = blockIdx.x * 256 + threadIdx.x;
    int node = gt >> 6, lane = gt & 63;
    if (node >= NN) return;
    const float* row = x + (size_t)node * 128;
    float2 v = *(const float2*)&row[lane * 2];
    float sum = v.x + v.y, sq = v.x * v.x + v.y * v.y;
    #pragma unroll
    for (int off = 32; off; off >>= 1) { sum += __shfl_xor(sum, off); sq += __shfl_xor(sq, off); }
    float mu = sum * (1.f / 128.f);
    float var = sq * (1.f / 128.f) - mu * mu;
    float rs = rsqrtf(var + 1e-6f);
    float o0 = (v.x - mu) * rs * s[lane * 2] + b[lane * 2];
    float o1 = (v.y - mu) * rs * s[lane * 2 + 1] + b[lane * 2 + 1];
    ((uint32_t*)xn_b)[(size_t)node * 64 + lane] = pk2(o0, o1);
  } else if (blockIdx.x < 15000) {
    int i = (blockIdx.x - 5000) * 256 + threadIdx.x;  // NN*128 triples
    if (i >= NN * 128) return;
    int n = i >> 7, j = i & 127;
    const float* vr = vec + (size_t)n * 384 + j;
    uint16_t* cb = &combo[(size_t)n * 768 + j * 6];
    cb[3] = f2bf(vr[0]);                          // w0
    *(uint32_t*)&cb[4] = pk2(vr[128], vr[256]);   // w1|w2 (4B aligned)
  } else {
    int i = (blockIdx.x - 15000) * 256 + threadIdx.x; // zero NN*512 floats as float4
    if (i >= NN * 128) return;
    dz[i] = make_float4(0.f, 0.f, 0.f, 0.f);
  }
}

// ---------------- edge sort by receiver (counting sort, parallel scan) ----------------
__global__ void k_hist(const int* __restrict__ rcv, int* __restrict__ deg) {
  int e = blockIdx.x * 256 + threadIdx.x;
  if (e < NE) atomicAdd(&deg[rcv[e]], 1);
}

__global__ void k_scan1(const int* __restrict__ deg, int* __restrict__ bsum) {
  __shared__ int ws[4];
  int i = blockIdx.x * 256 + threadIdx.x;
  int x = (i < NN) ? deg[i] : 0;
  #pragma unroll
  for (int d = 32; d; d >>= 1) x += __shfl_xor(x, d);
  if ((threadIdx.x & 63) == 0) ws[threadIdx.x >> 6] = x;
  __syncthreads();
  if (threadIdx.x == 0) bsum[blockIdx.x] = ws[0] + ws[1] + ws[2] + ws[3];
}

__global__ void k_scan2(int* __restrict__ bsum, int nb, int* __restrict__ off) {
  int lane = threadIdx.x;
  int carry = 0;
  for (int base = 0; base < nb; base += 64) {
    int i = base + lane;
    int x = (i < nb) ? bsum[i] : 0;
    int v = x;
    #pragma unroll
    for (int d = 1; d < 64; d <<= 1) { int y = __shfl_up(v, d); if (lane >= d) v += y; }
    if (i < nb) bsum[i] = carry + v - x;
    carry += __shfl(v, 63);
  }
  if (lane == 0) off[NN] = carry;
}

__global__ void k_scan3(const int* __restrict__ deg, const int* __restrict__ bsum,
                        int* __restrict__ off, int* __restrict__ cur) {
  __shared__ int ws[4];
  int t = threadIdx.x, lane = t & 63, w = t >> 6;
  int i = blockIdx.x * 256 + t;
  int x = (i < NN) ? deg[i] : 0;
  int v = x;
  #pragma unroll
  for (int d = 1; d < 64; d <<= 1) { int y = __shfl_up(v, d); if (lane >= d) v += y; }
  if (lane == 63) ws[w] = v;
  __syncthreads();
  int wadd = 0;
  for (int j = 0; j < w; j++) wadd += ws[j];
  int excl = bsum[blockIdx.x] + wadd + v - x;
  if (i < NN) { off[i] = excl; cur[i] = excl; }
}

__global__ void k_scatter(const int* __restrict__ rcv, int* __restrict__ cur,
                          int* __restrict__ perm) {
  int e = blockIdx.x * 256 + threadIdx.x;
  if (e >= NE) return;
  int pos = atomicAdd(&cur[rcv[e]], 1);
  perm[pos] = e;
}

// permute per-edge scalars into sorted order; cutoff precomputed into edata.w
__global__ void k_permute(const int* __restrict__ perm, const int* __restrict__ snd,
                          const int* __restrict__ rcv, const float* __restrict__ ew,
                          const float* __restrict__ evec, int* __restrict__ sndp,
                          int* __restrict__ rcvp, float4* __restrict__ edata) {
  int i = blockIdx.x * 256 + threadIdx.x;
  if (i >= NE) return;
  int e = perm[i];
  sndp[i] = snd[e];
  rcvp[i] = rcv[e];
  float w = ew[e];
  float cut = (w < 5.f) ? 0.5f * (__cosf(w * 0.628318530717958648f) + 1.f) : 0.f;
  edata[i] = make_float4(evec[e * 3], evec[e * 3 + 1], evec[e * 3 + 2], cut);
}

// ---------------- bf16 MFMA GEMM: C = act(A @ BT^T + bias) ----------------
// AF32: A is f32, cast to bf16 during LDS staging.
template <int KTOT, bool OUT_BF16, bool SILU, bool AF32>
__global__ __launch_bounds__(256) void k_gemm(const void* __restrict__ A,
                                              const uint16_t* __restrict__ BT,
                                              const float* __restrict__ bias,
                                              void* __restrict__ Cout, int M, int Fo) {
  __shared__ __align__(16) uint16_t As[128 * 72];
  __shared__ __align__(16) uint16_t Bs[128 * 72];
  const uint16_t* A16 = (const uint16_t*)A;
  const float* A32 = (const float*)A;
  int t = threadIdx.x;
  int l = t & 63;
  int row0 = blockIdx.y * 128, col0 = blockIdx.x * 128;
  int wm = ((t >> 6) >> 1) * 64, wn = ((t >> 6) & 1) * 64;
  f32x4 acc[4][4] = {};
  for (int kt = 0; kt < KTOT; kt += 64) {
    __syncthreads();
    #pragma unroll
    for (int i = 0; i < 4; i++) {
      int c = i * 256 + t;
      int row = c >> 3, ko = (c & 7) * 8;
      uint4 av = make_uint4(0u, 0u, 0u, 0u);
      int gr = row0 + row;
      if (gr < M) {
        if (AF32) {
          float4 f0 = *(const float4*)&A32[(size_t)gr * KTOT + kt + ko];
          float4 f1 = *(const float4*)&A32[(size_t)gr * KTOT + kt + ko + 4];
          av = make_uint4(pk2(f0.x, f0.y), pk2(f0.z, f0.w), pk2(f1.x, f1.y), pk2(f1.z, f1.w));
        } else {
          av = *(const uint4*)&A16[(size_t)gr * KTOT + kt + ko];
        }
      }
      *(uint4*)&As[row * 72 + ko] = av;
      uint4 bw = *(const uint4*)&BT[(size_t)(col0 + row) * KTOT + kt + ko];
      *(uint4*)&Bs[row * 72 + ko] = bw;
    }
    __syncthreads();
    #pragma unroll
    for (int kk = 0; kk < 64; kk += 32) {
      bf16x8 af[4], bfr[4];
      #pragma unroll
      for (int mf = 0; mf < 4; mf++)
        af[mf] = *(const bf16x8*)&As[(wm + mf * 16 + (l & 15)) * 72 + (l >> 4) * 8 + kk];
      #pragma unroll
      for (int nf = 0; nf < 4; nf++)
        bfr[nf] = *(const bf16x8*)&Bs[(wn + nf * 16 + (l & 15)) * 72 + (l >> 4) * 8 + kk];
      #pragma unroll
      for (int mf = 0; mf < 4; mf++)
        #pragma unroll
        for (int nf = 0; nf < 4; nf++)
          acc[mf][nf] = __builtin_amdgcn_mfma_f32_16x16x32_bf16(af[mf], bfr[nf], acc[mf][nf], 0, 0, 0);
    }
  }
  float* Cf = (float*)Cout;
  uint16_t* Cb = (uint16_t*)Cout;
  #pragma unroll
  for (int mf = 0; mf < 4; mf++) {
    #pragma unroll
    for (int r = 0; r < 4; r++) {
      int grow = row0 + wm + mf * 16 + (l >> 4) * 4 + r;
      if (grow >= M) continue;
      #pragma unroll
      for (int nf = 0; nf < 4; nf++) {
        int gcol = col0 + wn + nf * 16 + (l & 15);
        float v = acc[mf][nf][r];
        if (bias) v += bias[gcol];
        if (SILU) v = siluf(v);
        if (OUT_BF16) Cb[(size_t)grow * Fo + gcol] = f2bf(v);
        else          Cf[(size_t)grow * Fo + gcol] = v;
      }
    }
  }
}

// ---------------- qkv GEMM: plain epilogue; q/k -> qk_raw [NN,256], v -> combo slots ----------------
__global__ __launch_bounds__(256) void k_gemm_qkv2(
    const uint16_t* __restrict__ A, const uint16_t* __restrict__ BT,
    const float* __restrict__ bias, uint16_t* __restrict__ qk_raw,
    uint16_t* __restrict__ combo) {
  __shared__ __align__(16) uint16_t As[128 * 72];
  __shared__ __align__(16) uint16_t Bs[128 * 72];
  int t = threadIdx.x;
  int l = t & 63;
  int row0 = blockIdx.y * 128, col0 = blockIdx.x * 128;
  int wm = ((t >> 6) >> 1) * 64, wn = ((t >> 6) & 1) * 64;
  f32x4 acc[4][4] = {};
  for (int kt = 0; kt < 128; kt += 64) {
    __syncthreads();
    #pragma unroll
    for (int i = 0; i < 4; i++) {
      int c = i * 256 + t;
      int row = c >> 3, ko = (c & 7) * 8;
      uint4 av = make_uint4(0u, 0u, 0u, 0u);
      int gr = row0 + row;
      if (gr < NN) av = *(const uint4*)&A[(size_t)gr * 128 + kt + ko];
      *(uint4*)&As[row * 72 + ko] = av;
      uint4 bw = *(const uint4*)&BT[(size_t)(col0 + row) * 128 + kt + ko];
      *(uint4*)&Bs[row * 72 + ko] = bw;
    }
    __syncthreads();
    #pragma unroll
    for (int kk = 0; kk < 64; kk += 32) {
      bf16x8 af[4], bfr[4];
      #pragma unroll
      for (int mf = 0; mf < 4; mf++)
        af[mf] = *(const bf16x8*)&As[(wm + mf * 16 + (l & 15)) * 72 + (l >> 4) * 8 + kk];
      #pragma unroll
      for (int nf = 0; nf < 4; nf++)
        bfr[nf] = *(const bf16x8*)&Bs[(wn + nf * 16 + (l & 15)) * 72 + (l >> 4) * 8 + kk];
      #pragma unroll
      for (int mf = 0; mf < 4; mf++)
        #pragma unroll
        for (int nf = 0; nf < 4; nf++)
          acc[mf][nf] = __builtin_amdgcn_mfma_f32_16x16x32_bf16(af[mf], bfr[nf], acc[mf][nf], 0, 0, 0);
    }
  }
  int d = l & 15;
  #pragma unroll
  for (int mf = 0; mf < 4; mf++) {
    #pragma unroll
    for (int r = 0; r < 4; r++) {
      int grow = row0 + wm + mf * 16 + (l >> 4) * 4 + r;
      if (grow >= NN) continue;
      #pragma unroll
      for (int nf = 0; nf < 4; nf++) {
        int gcol = col0 + wn + nf * 16 + d;
        float v = acc[mf][nf][r] + bias[gcol];
        if (col0 < 256) {
          qk_raw[(size_t)grow * 256 + gcol] = f2bf(v);
        } else {
          int j2 = gcol - 256, j = j2 >> 2, c = j2 & 3;
          if (c < 3) combo[(size_t)grow * 768 + j * 6 + c] = f2bf(v);
        }
      }
    }
  }
}

// ---------------- per-head LN on q/k (bf16 in/out, qk_raw stride 256) ----------------
__global__ void k_headln(const uint16_t* __restrict__ qkv, const float* __restrict__ qs,
                         const float* __restrict__ qb, const float* __restrict__ ks,
                         const float* __restrict__ kb, uint16_t* __restrict__ out) {
  int idx = blockIdx.x * 256 + threadIdx.x;
  if (idx >= NN * 16) return;
  int n = idx >> 4, ph = idx & 15, part = ph >> 3, h = ph & 7;
  const uint16_t* src = qkv + (size_t)n * 256 + part * 128 + h * 16;
  float v[16], sum = 0.f;
  #pragma unroll
  for (int i = 0; i < 16; i++) { v[i] = bf2f(src[i]); sum += v[i]; }
  float mu = sum * (1.f / 16.f), var = 0.f;
  #pragma unroll
  for (int i = 0; i < 16; i++) { float dd = v[i] - mu; var += dd * dd; }
  float rs = rsqrtf(var * (1.f / 16.f) + 1e-6f);
  const float* sc = part ? ks : qs;
  const float* bb = part ? kb : qb;
  uint16_t* dst = out + (size_t)n * 256 + part * 128 + h * 16;
  #pragma unroll
  for (int i = 0; i < 16; i++) dst[i] = f2bf((v[i] - mu) * rs * sc[i] + bb[i]);
}

// ---------------- o-GEMM with fused final epilogue (proven R10/R11) ----------------
__device__ __forceinline__ void o_pass(const float* __restrict__ A32,
                                       const uint16_t* __restrict__ BT, int row0, int cb,
                                       int t, int l, int wm, int wn,
                                       uint16_t* As, uint16_t* Bs, f32x4 (&acc)[4][4]) {
  for (int kt = 0; kt < 128; kt += 64) {
    __syncthreads();
    #pragma unroll
    for (int i = 0; i < 4; i++) {
      int c = i * 256 + t;
      int row = c >> 3, ko = (c & 7) * 8;
      uint4 av = make_uint4(0u, 0u, 0u, 0u);
      int gr = row0 + row;
      if (gr < NN) {
        float4 f0 = *(const float4*)&A32[(size_t)gr * 128 + kt + ko];
        float4 f1 = *(const float4*)&A32[(size_t)gr * 128 + kt + ko + 4];
        av = make_uint4(pk2(f0.x, f0.y), pk2(f0.z, f0.w), pk2(f1.x, f1.y), pk2(f1.z, f1.w));
      }
      *(uint4*)&As[row * 72 + ko] = av;
      uint4 bw = *(const uint4*)&BT[(size_t)(cb * 128 + row) * 128 + kt + ko];
      *(uint4*)&Bs[row * 72 + ko] = bw;
    }
    __syncthreads();
    #pragma unroll
    for (int kk = 0; kk < 64; kk += 32) {
      bf16x8 af[4], bfr[4];
      #pragma unroll
      for (int mf = 0; mf < 4; mf++)
        af[mf] = *(const bf16x8*)&As[(wm + mf * 16 + (l & 15)) * 72 + (l >> 4) * 8 + kk];
      #pragma unroll
      for (int nf = 0; nf < 4; nf++)
        bfr[nf] = *(const bf16x8*)&Bs[(wn + nf * 16 + (l & 15)) * 72 + (l >> 4) * 8 + kk];
      #pragma unroll
      for (int mf = 0; mf < 4; mf++)
        #pragma unroll
        for (int nf = 0; nf < 4; nf++)
          acc[mf][nf] = __builtin_amdgcn_mfma_f32_16x16x32_bf16(af[mf], bfr[nf], acc[mf][nf], 0, 0, 0);
    }
  }
}

__global__ __launch_bounds__(256) void k_gemm_o(
    const uint16_t* __restrict__ BT, const float* __restrict__ bo,
    const uint16_t* __restrict__ vp, float* __restrict__ dout) {
  __shared__ __align__(16) uint16_t As[128 * 72];
  __shared__ __align__(16) uint16_t Bs[128 * 72];
  float* xagg = dout;
  float* vecagg = dout + (size_t)NN * 128;
  int t = threadIdx.x;
  int l = t & 63;
  int row0 = blockIdx.y * 128;
  int wm = ((t >> 6) >> 1) * 64, wn = ((t >> 6) & 1) * 64;
  f32x4 acc0[4][4] = {}, acc1[4][4] = {}, acc2[4][4] = {};
  o_pass(xagg, BT, row0, 0, t, l, wm, wn, As, Bs, acc0);
  o_pass(xagg, BT, row0, 1, t, l, wm, wn, As, Bs, acc1);
  o_pass(xagg, BT, row0, 2, t, l, wm, wn, As, Bs, acc2);
  int d = l & 15;
  #pragma unroll
  for (int mf = 0; mf < 4; mf++) {
    #pragma unroll
    for (int r = 0; r < 4; r++) {
      int grow = row0 + wm + mf * 16 + (l >> 4) * 4 + r;
      if (grow >= NN) continue;
      const uint16_t* vpn = vp + (size_t)grow * 1152;
      #pragma unroll
      for (int nf = 0; nf < 4; nf++) {
        int col = wn + nf * 16 + d;
        float o1 = acc0[mf][nf][r] + bo[col];
        float o2 = acc1[mf][nf][r] + bo[128 + col];
        float o3 = acc2[mf][nf][r] + bo[256 + col];
        float vd = 0.f;
        #pragma unroll
        for (int c = 0; c < 3; c++)
          vd += bf2f(vpn[c * 384 + col]) * bf2f(vpn[c * 384 + 128 + col]);
        xagg[(size_t)grow * 128 + col] = vd * o2 + o3;
        #pragma unroll
        for (int c = 0; c < 3; c++) {
          size_t vi = ((size_t)grow * 3 + c) * 128 + col;
          vecagg[vi] = bf2f(vpn[c * 384 + 256 + col]) * o1 + vecagg[vi];
        }
      }
    }
  }
}

// ---------------- FULLY FUSED edge phase (combo 12B walk + dk plane; in-kernel ea gather) ----------------
#define MTS 516   // walk-tile row stride (shorts): slots 0=xm 1=m1 2=m2, 3 pad

__device__ __forceinline__ void mfma32(const uint16_t* As, int r0,
                                       const uint16_t* __restrict__ BT2, int cb,
                                       int wn, int l, f32x4 acc[2][2]) {
  #pragma unroll
  for (int kk = 0; kk < 2; kk++) {
    bf16x8 af[2];
    #pragma unroll
    for (int mf = 0; mf < 2; mf++)
      af[mf] = *(const bf16x8*)&As[(r0 + mf * 16 + (l & 15)) * 68 + (l >> 4) * 8 + kk * 32];
    #pragma unroll
    for (int nf = 0; nf < 2; nf++) {
      bf16x8 bv = *(const bf16x8*)&BT2[(size_t)(cb * 128 + wn + nf * 16 + (l & 15)) * 64 +
                                       (l >> 4) * 8 + kk * 32];
      #pragma unroll
      for (int mf = 0; mf < 2; mf++)
        acc[mf][nf] = __builtin_amdgcn_mfma_f32_16x16x32_bf16(af[mf], bv, acc[mf][nf], 0, 0, 0);
    }
  }
}

__device__ __forceinline__ void silu_slot(uint16_t* mt, const float bsv[2], int slot,
                                          int wn, int l, f32x4 acc[2][2]) {
  #pragma unroll
  for (int mf = 0; mf < 2; mf++)
    #pragma unroll
    for (int r = 0; r < 4; r++) {
      int row = mf * 16 + (l >> 4) * 4 + r;
      #pragma unroll
      for (int nf = 0; nf < 2; nf++) {
        int c = wn + nf * 16 + (l & 15);
        mt[row * MTS + c * 4 + slot] = f2bf(siluf(acc[mf][nf][r] + bsv[nf]));
      }
    }
}

__device__ __forceinline__ void silu_dk(uint16_t* mtd, const float bsv[2],
                                        int wn, int l, f32x4 acc[2][2]) {
  #pragma unroll
  for (int mf = 0; mf < 2; mf++)
    #pragma unroll
    for (int r = 0; r < 4; r++) {
      int row = mf * 16 + (l >> 4) * 4 + r;
      #pragma unroll
      for (int nf = 0; nf < 2; nf++) {
        int c = wn + nf * 16 + (l & 15);
        mtd[row * 140 + c] = f2bf(siluf(acc[mf][nf][r] + bsv[nf]));
      }
    }
}

__global__ __launch_bounds__(256) void k_edge_all(
    const float* __restrict__ ea, const int* __restrict__ perm,
    const int* __restrict__ sndp, const int* __restrict__ rcvp,
    const int* __restrict__ off, const float4* __restrict__ edata,
    const uint16_t* __restrict__ WT2, const float* __restrict__ Bd2,
    const uint16_t* __restrict__ qk_b, const uint16_t* __restrict__ combo,
    float* __restrict__ xagg, float* __restrict__ vecagg) {
  __shared__ __align__(16) uint16_t As[64 * 68];     // 8.7 KB
  __shared__ __align__(16) uint16_t mt[32 * MTS];    // 33 KB (xm,m1,m2 slots)
  __shared__ __align__(16) uint16_t mtd[32 * 140];   // 8.96 KB (dk)
  __shared__ float attn_l[32 * 8];                   // 1 KB
  __shared__ int sndl[64], rcvl[64], lo_g[64], hi_g[64];
  __shared__ float4 ed4[64];

  int e0 = blockIdx.x * 64;
  int t = threadIdx.x, l = t & 63, wn = (t >> 6) * 32;

  // ---- meta + A stage (in-kernel gather, f32 -> bf16) + bias regs ----
  if (t < 64) {
    int e = e0 + t;
    int r = rcvp[e];
    sndl[t] = sndp[e]; rcvl[t] = r;
    lo_g[t] = off[r]; hi_g[t] = off[r + 1];
    ed4[t] = edata[e];
  }
  {
    int row = t >> 2, qo = (t & 3) * 16;
    int pe = perm[e0 + row];
    const float* src = ea + (size_t)pe * 64 + qo;
    float4 f0 = *(const float4*)src;
    float4 f1 = *(const float4*)(src + 4);
    float4 f2 = *(const float4*)(src + 8);
    float4 f3 = *(const float4*)(src + 12);
    uint4 o0, o1;
    o0.x = pk2(f0.x, f0.y); o0.y = pk2(f0.z, f0.w);
    o0.z = pk2(f1.x, f1.y); o0.w = pk2(f1.z, f1.w);
    o1.x = pk2(f2.x, f2.y); o1.y = pk2(f2.z, f2.w);
    o1.z = pk2(f3.x, f3.y); o1.w = pk2(f3.z, f3.w);
    *(uint4*)&As[row * 68 + qo] = o0;
    *(uint4*)&As[row * 68 + qo + 8] = o1;
  }
  float bs[4][2];
  #pragma unroll
  for (int cb = 0; cb < 4; cb++) {
    bs[cb][0] = Bd2[cb * 128 + wn + (l & 15)];
    bs[cb][1] = Bd2[cb * 128 + wn + 16 + (l & 15)];
  }
  __syncthreads();

  #pragma unroll
  for (int half = 0; half < 2; half++) {
    int r0 = half * 32;
    // ---- P1: cb0 dk -> mtd ----
    { f32x4 acc[2][2] = {}; mfma32(As, r0, WT2, 0, wn, l, acc); silu_dk(mtd, bs[0], wn, l, acc); }
    __syncthreads();
    // ---- P2: q/k loads early, cb1-3 MFMA hide them, then attn dot ----
    {
      int el = t >> 3, h = t & 7;
      int ge = r0 + el;
      int rn = rcvl[ge], sn = sndl[ge];
      const uint16_t* qb_ = qk_b + (size_t)rn * 256 + h * 16;
      const uint16_t* kb_ = qk_b + (size_t)sn * 256 + 128 + h * 16;
      uint4 q0 = *(const uint4*)qb_;
      uint4 q1 = *(const uint4*)(qb_ + 8);
      uint4 k0 = *(const uint4*)kb_;
      uint4 k1 = *(const uint4*)(kb_ + 8);
      { f32x4 acc[2][2] = {}; mfma32(As, r0, WT2, 1, wn, l, acc); silu_slot(mt, bs[1], 0, wn, l, acc); }
      { f32x4 acc[2][2] = {}; mfma32(As, r0, WT2, 2, wn, l, acc); silu_slot(mt, bs[2], 1, wn, l, acc); }
      { f32x4 acc[2][2] = {}; mfma32(As, r0, WT2, 3, wn, l, acc); silu_slot(mt, bs[3], 2, wn, l, acc); }
      const uint32_t* dp = (const uint32_t*)&mtd[el * 140 + h * 16];
      uint32_t qa[8] = {q0.x, q0.y, q0.z, q0.w, q1.x, q1.y, q1.z, q1.w};
      uint32_t ka[8] = {k0.x, k0.y, k0.z, k0.w, k1.x, k1.y, k1.z, k1.w};
      float dot = 0.f;
      #pragma unroll
      for (int j = 0; j < 8; j++) dot += prod2(qa[j], ka[j], dp[j]);
      attn_l[el * 8 + h] = siluf(dot) * ed4[ge].w;
    }
    __syncthreads();
    // ---- P3: merged walk; 12B combo gather per (edge,col) ----
    {
      int col = t & 127, sub = t >> 7;
      int i0 = r0 + sub * 16, i1 = i0 + 16;
      int ha = col >> 4;
      float accx = 0.f, a0 = 0.f, a1 = 0.f, a2 = 0.f;
      #pragma unroll 8
      for (int i = i0; i < i1; i++) {
        int li = i - r0;
        int n = rcvl[i], s = sndl[i];
        const uint16_t* cp = &combo[(size_t)s * 768 + col * 6];
        uint32_t u0 = *(const uint32_t*)cp;        // v0|v1
        uint32_t u1 = *(const uint32_t*)(cp + 2);  // v2|w0
        uint32_t u2 = *(const uint32_t*)(cp + 4);  // w1|w2
        uint2 mr = *(const uint2*)&mt[li * MTS + col * 4];
        float a = attn_l[li * 8 + ha];
        float xmv = bf2f(mr.x & 0xffffu), m1v = bf2f(mr.x >> 16), m2v = bf2f(mr.y & 0xffffu);
        accx += bf2f(u0 & 0xffffu) * xmv * a;
        float mm1 = bf2f(u0 >> 16) * m1v;
        float mm2 = bf2f(u1 & 0xffffu) * m2v;
        float4 ev = ed4[i];
        a0 += bf2f(u1 >> 16)     * mm1 + ev.x * mm2;
        a1 += bf2f(u2 & 0xffffu) * mm1 + ev.y * mm2;
        a2 += bf2f(u2 >> 16)     * mm1 + ev.z * mm2;
        if (i == i1 - 1 || rcvl[i + 1] != n) {
          bool cont = (lo_g[i] >= e0 + i0) && (hi_g[i] <= e0 + i1);
          float* dx_ = &xagg[(size_t)n * 128 + col];
          float* d0 = &vecagg[((size_t)n * 3 + 0) * 128 + col];
          float* d1 = &vecagg[((size_t)n * 3 + 1) * 128 + col];
          float* d2 = &vecagg[((size_t)n * 3 + 2) * 128 + col];
          if (cont) { *dx_ = accx; *d0 = a0; *d1 = a1; *d2 = a2; }
          else { atomicAdd(dx_, accx); atomicAdd(d0, a0); atomicAdd(d1, a1); atomicAdd(d2, a2); }
          accx = a0 = a1 = a2 = 0.f;
        }
      }
    }
    __syncthreads();
  }
}

static inline int cdiv_i(long long a, long long b) { return (int)((a + b - 1) / b); }

extern "C" void kernel_launch(void* const* d_in, const int* in_sizes, int n_in,
                              void* d_out, int out_size, void* d_ws, size_t ws_size,
                              hipStream_t stream) {
  const float* x    = (const float*)d_in[0];
  const float* vec  = (const float*)d_in[1];
  const float* ew   = (const float*)d_in[2];
  const float* ea   = (const float*)d_in[3];
  const float* evec = (const float*)d_in[4];
  const int*   snd  = (const int*)d_in[5];
  const int*   rcv  = (const int*)d_in[6];
  const float* ln_s = (const float*)d_in[7];
  const float* ln_b = (const float*)d_in[8];
  const float* Wq = (const float*)d_in[9];   const float* bq = (const float*)d_in[10];
  const float* Wk = (const float*)d_in[11];  const float* bk = (const float*)d_in[12];
  const float* Wv = (const float*)d_in[13];  const float* bv = (const float*)d_in[14];
  const float* Wvec = (const float*)d_in[15];
  const float* Wdk = (const float*)d_in[16]; const float* bdk = (const float*)d_in[17];
  const float* Wdv = (const float*)d_in[18]; const float* bdv = (const float*)d_in[19];
  const float* Wo = (const float*)d_in[20];  const float* bo = (const float*)d_in[21];
  const float* qln_s = (const float*)d_in[22]; const float* qln_b = (const float*)d_in[23];
  const float* kln_s = (const float*)d_in[24]; const float* kln_b = (const float*)d_in[25];
  (void)in_sizes; (void)n_in; (void)out_size; (void)ws_size;

  uint8_t* p = (uint8_t*)d_ws;
  auto alloc = [&](size_t bytes) -> uint8_t* {
    uint8_t* r = p; p += (bytes + 255) & ~(size_t)255; return r;
  };
  uint16_t* WTqkv = (uint16_t*)alloc(768 * 128 * 2);
  float*    Bqkv  = (float*)alloc(768 * 4);
  uint16_t* WTvec = (uint16_t*)alloc(384 * 128 * 2);
  uint16_t* WTdkv = (uint16_t*)alloc(512 * 64 * 2);
  float*    Bdkv  = (float*)alloc(512 * 4);
  uint16_t* WTo   = (uint16_t*)alloc(384 * 128 * 2);
  int*      deg   = (int*)alloc(NN * 4);
  int*      off   = (int*)alloc((NN + 1) * 4);
  int*      cur   = (int*)alloc(NN * 4);
  int*      bsum  = (int*)alloc(256 * 4);
  int*      perm  = (int*)alloc((size_t)NE * 4);
  int*      sndp  = (int*)alloc((size_t)NE * 4);
  int*      rcvp  = (int*)alloc((size_t)NE * 4);
  float4*   edata = (float4*)alloc((size_t)NE * 16);
  uint16_t* xn_b  = (uint16_t*)alloc((size_t)NN * 128 * 2);
  uint16_t* qk_raw = (uint16_t*)alloc((size_t)NN * 256 * 2);
  uint16_t* qk_b  = (uint16_t*)alloc((size_t)NN * 256 * 2);
  uint16_t* combo = (uint16_t*)alloc((size_t)NN * 768 * 2);
  uint16_t* vp    = (uint16_t*)alloc((size_t)NN * 3 * 384 * 2);

  float* xagg   = (float*)d_out;
  float* vecagg = (float*)d_out + (size_t)NN * 128;

  // ---- weights prep (1 launch) ----
  k_prep<<<cdiv_i(98304 + 49152 + 32768 + 49152 + 1280, 256), 256, 0, stream>>>(
      Wq, Wk, Wv, Wvec, Wdk, Wdv, Wo, bq, bk, bv, bdk, bdv,
      WTqkv, WTvec, WTdkv, WTo, Bqkv, Bdkv);

  // ---- edge sort by receiver ----
  int NSB = cdiv_i(NN, 256);
  hipMemsetAsync(deg, 0, NN * 4, stream);
  k_hist<<<cdiv_i(NE, 256), 256, 0, stream>>>(rcv, deg);
  k_scan1<<<NSB, 256, 0, stream>>>(deg, bsum);
  k_scan2<<<1, 64, 0, stream>>>(bsum, NSB, off);
  k_scan3<<<NSB, 256, 0, stream>>>(deg, bsum, off, cur);
  k_scatter<<<cdiv_i(NE, 256), 256, 0, stream>>>(rcv, cur, perm);
  k_permute<<<cdiv_i(NE, 256), 256, 0, stream>>>(perm, snd, rcv, ew, evec, sndp, rcvp, edata);

  // ---- node pre (LN + combo w-slots + zero d_out) ----
  k_node_pre<<<25000, 256, 0, stream>>>(x, ln_s, ln_b, vec, xn_b, combo, (float4*)d_out);

  // qkv GEMM: q/k plain -> qk_raw; v -> combo slots 0-2
  { dim3 g(6, cdiv_i(NN, 128));
    k_gemm_qkv2<<<g, 256, 0, stream>>>(xn_b, WTqkv, Bqkv, qk_raw, combo); }
  k_headln<<<cdiv_i((long long)NN * 16, 256), 256, 0, stream>>>(qk_raw, qln_s, qln_b,
                                                               kln_s, kln_b, qk_b);

  // vp = vec @ Wvec (f32 A staged to bf16; bf16 out)
  { dim3 g(384 / 128, cdiv_i((long long)NN * 3, 128));
    k_gemm<128, true, false, true><<<g, 256, 0, stream>>>(vec, WTvec, nullptr, vp, NN * 3, 384); }

  // ---- fully fused edge phase (in-kernel ea gather) ----
  k_edge_all<<<NE / 64, 256, 0, stream>>>(ea, perm, sndp, rcvp, off, edata, WTdkv, Bdkv,
                                          qk_b, combo, xagg, vecagg);

  // ---- o-GEMM with fused final epilogue (in-place on d_out) ----
  { dim3 g(1, cdiv_i(NN, 128));
    k_gemm_o<<<g, 256, 0, stream>>>(WTo, bo, vp, (float*)d_out); }
}

// Round 17
// 330.113 us; speedup vs baseline: 1.0790x; 1.0239x over previous
//
#include <hip/hip_runtime.h>
#include <stdint.h>

#define NN 20000
#define NE 200000   // == 3125 * 64 exactly (k_edge_all assumes this)
// H=128, NH=8, HD=16, RBF=64

typedef __attribute__((ext_vector_type(8))) short bf16x8;
typedef __attribute__((ext_vector_type(4))) float f32x4;

__device__ __forceinline__ float bf2f(uint32_t u) {
  union { uint32_t i; float f; } v; v.i = u << 16; return v.f;
}
__device__ __forceinline__ uint16_t f2bf(float f) {
  union { float f; uint32_t i; } v; v.f = f;
  return (uint16_t)((v.i + 0x7fffu + ((v.i >> 16) & 1u)) >> 16);
}
__device__ __forceinline__ uint32_t pk2(float lo, float hi) {
  return (uint32_t)f2bf(lo) | ((uint32_t)f2bf(hi) << 16);
}
__device__ __forceinline__ float siluf(float x) { return x / (1.f + __expf(-x)); }
__device__ __forceinline__ float prod2(uint32_t q2, uint32_t k2, uint32_t d2) {
  return bf2f(q2 & 0xffffu) * bf2f(k2 & 0xffffu) * bf2f(d2 & 0xffffu)
       + bf2f(q2 >> 16) * bf2f(k2 >> 16) * bf2f(d2 >> 16);
}

// ---------------- consolidated weight prep (one launch; also zeros deg) ----------------
// WTqkv [768][128]: rows 0-255 = q|k; rows 256-767 v INTERLEAVED
// (row 256 + j*4 + c, j=h*16+d, c=0..2 from orig col h*48+c*16+d, c==3 pad).
// WTdkv2 [512][64] column-reordered: dk | xm | m1 | m2.
__global__ void k_prep(const float* __restrict__ Wq, const float* __restrict__ Wk,
                       const float* __restrict__ Wv, const float* __restrict__ Wvec,
                       const float* __restrict__ Wdk, const float* __restrict__ Wdv,
                       const float* __restrict__ Wo, const float* __restrict__ bq,
                       const float* __restrict__ bk, const float* __restrict__ bv,
                       const float* __restrict__ bdk, const float* __restrict__ bdv,
                       uint16_t* __restrict__ WTqkv, uint16_t* __restrict__ WTvec,
                       uint16_t* __restrict__ WTdkv2, uint16_t* __restrict__ WTo,
                       float* __restrict__ Bqkv, float* __restrict__ Bdkv2,
                       int* __restrict__ deg) {
  int idx = blockIdx.x * 256 + threadIdx.x;
  if (idx < 98304) {                       // WTqkv [768][128]
    int rr = idx >> 7, k = idx & 127;
    float v;
    if (rr < 128)      v = Wq[k * 128 + rr];
    else if (rr < 256) v = Wk[k * 128 + rr - 128];
    else {
      int j2 = rr - 256, j = j2 >> 2, c = j2 & 3;
      v = (c < 3) ? Wv[k * 384 + (j >> 4) * 48 + c * 16 + (j & 15)] : 0.f;
    }
    WTqkv[idx] = f2bf(v);
    return;
  }
  idx -= 98304;
  if (idx < 49152) {                       // WTvec [384][128]
    int c = idx >> 7, k = idx & 127;
    WTvec[idx] = f2bf(Wvec[k * 384 + c]);
    return;
  }
  idx -= 49152;
  if (idx < 32768) {                       // WTdkv2 [512][64], reordered
    int rr = idx >> 6, k = idx & 63;
    float v;
    if (rr < 128) v = Wdk[k * 128 + rr];
    else {
      int j = rr - 128, p = j >> 7, hd = j & 127;
      v = Wdv[k * 384 + (hd >> 4) * 48 + p * 16 + (hd & 15)];
    }
    WTdkv2[idx] = f2bf(v);
    return;
  }
  idx -= 32768;
  if (idx < 49152) {                       // WTo [384][128]
    int c = idx >> 7, k = idx & 127;
    WTo[idx] = f2bf(Wo[k * 384 + c]);
    return;
  }
  idx -= 49152;
  if (idx < 768) {                         // Bqkv [768]
    if (idx < 128)      Bqkv[idx] = bq[idx];
    else if (idx < 256) Bqkv[idx] = bk[idx - 128];
    else {
      int j2 = idx - 256, j = j2 >> 2, c = j2 & 3;
      Bqkv[idx] = (c < 3) ? bv[(j >> 4) * 48 + c * 16 + (j & 15)] : 0.f;
    }
    return;
  }
  if (idx < 1280) {
    int t = idx - 768;
    if (t < 128) Bdkv2[t] = bdk[t];
    else {
      int j = t - 128, p = j >> 7, hd = j & 127;
      Bdkv2[t] = bdv[(hd >> 4) * 48 + p * 16 + (hd & 15)];
    }
    return;
  }
  idx -= 1280;
  if (idx < NN) deg[idx] = 0;              // zero degree histogram
}

// ---------------- node pre: LN(x)->bf16 + vec walk-slots of combo + zero d_out ----------------
__global__ void k_node_pre(const float* __restrict__ x, const float* __restrict__ s,
                           const float* __restrict__ b, const float* __restrict__ vec,
                           uint16_t* __restrict__ xn_b, uint16_t* __restrict__ combo,
                           float4* __restrict__ dz) {
  if (blockIdx.x < 5000) {
    int gt = blockIdx.x * 256 + threadIdx.x;
    int node = gt >> 6, lane = gt & 63;
    if (node >= NN) return;
    const float* row = x + (size_t)node * 128;
    float2 v = *(const float2*)&row[lane * 2];
    float sum = v.x + v.y, sq = v.x * v.x + v.y * v.y;
    #pragma unroll
    for (int off = 32; off; off >>= 1) { sum += __shfl_xor(sum, off); sq += __shfl_xor(sq, off); }
    float mu = sum * (1.f / 128.f);
    float var = sq * (1.f / 128.f) - mu * mu;
    float rs = rsqrtf(var + 1e-6f);
    float o0 = (v.x - mu) * rs * s[lane * 2] + b[lane * 2];
    float o1 = (v.y - mu) * rs * s[lane * 2 + 1] + b[lane * 2 + 1];
    ((uint32_t*)xn_b)[(size_t)node * 64 + lane] = pk2(o0, o1);
  } else if (blockIdx.x < 15000) {
    int i = (blockIdx.x - 5000) * 256 + threadIdx.x;  // NN*128 triples
    if (i >= NN * 128) return;
    int n = i >> 7, j = i & 127;
    const float* vr = vec + (size_t)n * 384 + j;
    uint16_t* cb = &combo[(size_t)n * 768 + j * 6];
    cb[3] = f2bf(vr[0]);                          // w0
    *(uint32_t*)&cb[4] = pk2(vr[128], vr[256]);   // w1|w2 (4B aligned)
  } else {
    int i = (blockIdx.x - 15000) * 256 + threadIdx.x; // zero NN*512 floats as float4
    if (i >= NN * 128) return;
    dz[i] = make_float4(0.f, 0.f, 0.f, 0.f);
  }
}

// ---------------- edge sort by receiver (counting sort, parallel scan) ----------------
__global__ void k_hist(const int* __restrict__ rcv, int* __restrict__ deg) {
  int e = blockIdx.x * 256 + threadIdx.x;
  if (e < NE) atomicAdd(&deg[rcv[e]], 1);
}

__global__ void k_scan1(const int* __restrict__ deg, int* __restrict__ bsum) {
  __shared__ int ws[4];
  int i = blockIdx.x * 256 + threadIdx.x;
  int x = (i < NN) ? deg[i] : 0;
  #pragma unroll
  for (int d = 32; d; d >>= 1) x += __shfl_xor(x, d);
  if ((threadIdx.x & 63) == 0) ws[threadIdx.x >> 6] = x;
  __syncthreads();
  if (threadIdx.x == 0) bsum[blockIdx.x] = ws[0] + ws[1] + ws[2] + ws[3];
}

__global__ void k_scan2(int* __restrict__ bsum, int nb, int* __restrict__ off) {
  int lane = threadIdx.x;
  int carry = 0;
  for (int base = 0; base < nb; base += 64) {
    int i = base + lane;
    int x = (i < nb) ? bsum[i] : 0;
    int v = x;
    #pragma unroll
    for (int d = 1; d < 64; d <<= 1) { int y = __shfl_up(v, d); if (lane >= d) v += y; }
    if (i < nb) bsum[i] = carry + v - x;
    carry += __shfl(v, 63);
  }
  if (lane == 0) off[NN] = carry;
}

__global__ void k_scan3(const int* __restrict__ deg, const int* __restrict__ bsum,
                        int* __restrict__ off, int* __restrict__ cur) {
  __shared__ int ws[4];
  int t = threadIdx.x, lane = t & 63, w = t >> 6;
  int i = blockIdx.x * 256 + t;
  int x = (i < NN) ? deg[i] : 0;
  int v = x;
  #pragma unroll
  for (int d = 1; d < 64; d <<= 1) { int y = __shfl_up(v, d); if (lane >= d) v += y; }
  if (lane == 63) ws[w] = v;
  __syncthreads();
  int wadd = 0;
  for (int j = 0; j < w; j++) wadd += ws[j];
  int excl = bsum[blockIdx.x] + wadd + v - x;
  if (i < NN) { off[i] = excl; cur[i] = excl; }
}

__global__ void k_scatter(const int* __restrict__ rcv, int* __restrict__ cur,
                          int* __restrict__ perm) {
  int e = blockIdx.x * 256 + threadIdx.x;
  if (e >= NE) return;
  int pos = atomicAdd(&cur[rcv[e]], 1);
  perm[pos] = e;
}

// permute per-edge scalars into sorted order; cutoff precomputed into edata.w
__global__ void k_permute(const int* __restrict__ perm, const int* __restrict__ snd,
                          const int* __restrict__ rcv, const float* __restrict__ ew,
                          const float* __restrict__ evec, int* __restrict__ sndp,
                          int* __restrict__ rcvp, float4* __restrict__ edata) {
  int i = blockIdx.x * 256 + threadIdx.x;
  if (i >= NE) return;
  int e = perm[i];
  sndp[i] = snd[e];
  rcvp[i] = rcv[e];
  float w = ew[e];
  float cut = (w < 5.f) ? 0.5f * (__cosf(w * 0.628318530717958648f) + 1.f) : 0.f;
  edata[i] = make_float4(evec[e * 3], evec[e * 3 + 1], evec[e * 3 + 2], cut);
}

// ---------------- bf16 MFMA GEMM: C = act(A @ BT^T + bias) ----------------
// AF32: A is f32, cast to bf16 during LDS staging.
template <int KTOT, bool OUT_BF16, bool SILU, bool AF32>
__global__ __launch_bounds__(256) void k_gemm(const void* __restrict__ A,
                                              const uint16_t* __restrict__ BT,
                                              const float* __restrict__ bias,
                                              void* __restrict__ Cout, int M, int Fo) {
  __shared__ __align__(16) uint16_t As[128 * 72];
  __shared__ __align__(16) uint16_t Bs[128 * 72];
  const uint16_t* A16 = (const uint16_t*)A;
  const float* A32 = (const float*)A;
  int t = threadIdx.x;
  int l = t & 63;
  int row0 = blockIdx.y * 128, col0 = blockIdx.x * 128;
  int wm = ((t >> 6) >> 1) * 64, wn = ((t >> 6) & 1) * 64;
  f32x4 acc[4][4] = {};
  for (int kt = 0; kt < KTOT; kt += 64) {
    __syncthreads();
    #pragma unroll
    for (int i = 0; i < 4; i++) {
      int c = i * 256 + t;
      int row = c >> 3, ko = (c & 7) * 8;
      uint4 av = make_uint4(0u, 0u, 0u, 0u);
      int gr = row0 + row;
      if (gr < M) {
        if (AF32) {
          float4 f0 = *(const float4*)&A32[(size_t)gr * KTOT + kt + ko];
          float4 f1 = *(const float4*)&A32[(size_t)gr * KTOT + kt + ko + 4];
          av = make_uint4(pk2(f0.x, f0.y), pk2(f0.z, f0.w), pk2(f1.x, f1.y), pk2(f1.z, f1.w));
        } else {
          av = *(const uint4*)&A16[(size_t)gr * KTOT + kt + ko];
        }
      }
      *(uint4*)&As[row * 72 + ko] = av;
      uint4 bw = *(const uint4*)&BT[(size_t)(col0 + row) * KTOT + kt + ko];
      *(uint4*)&Bs[row * 72 + ko] = bw;
    }
    __syncthreads();
    #pragma unroll
    for (int kk = 0; kk < 64; kk += 32) {
      bf16x8 af[4], bfr[4];
      #pragma unroll
      for (int mf = 0; mf < 4; mf++)
        af[mf] = *(const bf16x8*)&As[(wm + mf * 16 + (l & 15)) * 72 + (l >> 4) * 8 + kk];
      #pragma unroll
      for (int nf = 0; nf < 4; nf++)
        bfr[nf] = *(const bf16x8*)&Bs[(wn + nf * 16 + (l & 15)) * 72 + (l >> 4) * 8 + kk];
      #pragma unroll
      for (int mf = 0; mf < 4; mf++)
        #pragma unroll
        for (int nf = 0; nf < 4; nf++)
          acc[mf][nf] = __builtin_amdgcn_mfma_f32_16x16x32_bf16(af[mf], bfr[nf], acc[mf][nf], 0, 0, 0);
    }
  }
  float* Cf = (float*)Cout;
  uint16_t* Cb = (uint16_t*)Cout;
  #pragma unroll
  for (int mf = 0; mf < 4; mf++) {
    #pragma unroll
    for (int r = 0; r < 4; r++) {
      int grow = row0 + wm + mf * 16 + (l >> 4) * 4 + r;
      if (grow >= M) continue;
      #pragma unroll
      for (int nf = 0; nf < 4; nf++) {
        int gcol = col0 + wn + nf * 16 + (l & 15);
        float v = acc[mf][nf][r];
        if (bias) v += bias[gcol];
        if (SILU) v = siluf(v);
        if (OUT_BF16) Cb[(size_t)grow * Fo + gcol] = f2bf(v);
        else          Cf[(size_t)grow * Fo + gcol] = v;
      }
    }
  }
}

// ---------------- qkv GEMM: plain epilogue; q/k -> qk_raw [NN,256], v -> combo slots ----------------
__global__ __launch_bounds__(256) void k_gemm_qkv2(
    const uint16_t* __restrict__ A, const uint16_t* __restrict__ BT,
    const float* __restrict__ bias, uint16_t* __restrict__ qk_raw,
    uint16_t* __restrict__ combo) {
  __shared__ __align__(16) uint16_t As[128 * 72];
  __shared__ __align__(16) uint16_t Bs[128 * 72];
  int t = threadIdx.x;
  int l = t & 63;
  int row0 = blockIdx.y * 128, col0 = blockIdx.x * 128;
  int wm = ((t >> 6) >> 1) * 64, wn = ((t >> 6) & 1) * 64;
  f32x4 acc[4][4] = {};
  for (int kt = 0; kt < 128; kt += 64) {
    __syncthreads();
    #pragma unroll
    for (int i = 0; i < 4; i++) {
      int c = i * 256 + t;
      int row = c >> 3, ko = (c & 7) * 8;
      uint4 av = make_uint4(0u, 0u, 0u, 0u);
      int gr = row0 + row;
      if (gr < NN) av = *(const uint4*)&A[(size_t)gr * 128 + kt + ko];
      *(uint4*)&As[row * 72 + ko] = av;
      uint4 bw = *(const uint4*)&BT[(size_t)(col0 + row) * 128 + kt + ko];
      *(uint4*)&Bs[row * 72 + ko] = bw;
    }
    __syncthreads();
    #pragma unroll
    for (int kk = 0; kk < 64; kk += 32) {
      bf16x8 af[4], bfr[4];
      #pragma unroll
      for (int mf = 0; mf < 4; mf++)
        af[mf] = *(const bf16x8*)&As[(wm + mf * 16 + (l & 15)) * 72 + (l >> 4) * 8 + kk];
      #pragma unroll
      for (int nf = 0; nf < 4; nf++)
        bfr[nf] = *(const bf16x8*)&Bs[(wn + nf * 16 + (l & 15)) * 72 + (l >> 4) * 8 + kk];
      #pragma unroll
      for (int mf = 0; mf < 4; mf++)
        #pragma unroll
        for (int nf = 0; nf < 4; nf++)
          acc[mf][nf] = __builtin_amdgcn_mfma_f32_16x16x32_bf16(af[mf], bfr[nf], acc[mf][nf], 0, 0, 0);
    }
  }
  int d = l & 15;
  #pragma unroll
  for (int mf = 0; mf < 4; mf++) {
    #pragma unroll
    for (int r = 0; r < 4; r++) {
      int grow = row0 + wm + mf * 16 + (l >> 4) * 4 + r;
      if (grow >= NN) continue;
      #pragma unroll
      for (int nf = 0; nf < 4; nf++) {
        int gcol = col0 + wn + nf * 16 + d;
        float v = acc[mf][nf][r] + bias[gcol];
        if (col0 < 256) {
          qk_raw[(size_t)grow * 256 + gcol] = f2bf(v);
        } else {
          int j2 = gcol - 256, j = j2 >> 2, c = j2 & 3;
          if (c < 3) combo[(size_t)grow * 768 + j * 6 + c] = f2bf(v);
        }
      }
    }
  }
}

// ---------------- per-head LN on q/k (bf16 in/out, qk_raw stride 256) ----------------
__global__ void k_headln(const uint16_t* __restrict__ qkv, const float* __restrict__ qs,
                         const float* __restrict__ qb, const float* __restrict__ ks,
                         const float* __restrict__ kb, uint16_t* __restrict__ out) {
  int idx = blockIdx.x * 256 + threadIdx.x;
  if (idx >= NN * 16) return;
  int n = idx >> 4, ph = idx & 15, part = ph >> 3, h = ph & 7;
  const uint16_t* src = qkv + (size_t)n * 256 + part * 128 + h * 16;
  float v[16], sum = 0.f;
  #pragma unroll
  for (int i = 0; i < 16; i++) { v[i] = bf2f(src[i]); sum += v[i]; }
  float mu = sum * (1.f / 16.f), var = 0.f;
  #pragma unroll
  for (int i = 0; i < 16; i++) { float dd = v[i] - mu; var += dd * dd; }
  float rs = rsqrtf(var * (1.f / 16.f) + 1e-6f);
  const float* sc = part ? ks : qs;
  const float* bb = part ? kb : qb;
  uint16_t* dst = out + (size_t)n * 256 + part * 128 + h * 16;
  #pragma unroll
  for (int i = 0; i < 16; i++) dst[i] = f2bf((v[i] - mu) * rs * sc[i] + bb[i]);
}

// ---------------- o-GEMM with fused final epilogue (proven R10/R11/R15) ----------------
__device__ __forceinline__ void o_pass(const float* __restrict__ A32,
                                       const uint16_t* __restrict__ BT, int row0, int cb,
                                       int t, int l, int wm, int wn,
                                       uint16_t* As, uint16_t* Bs, f32x4 (&acc)[4][4]) {
  for (int kt = 0; kt < 128; kt += 64) {
    __syncthreads();
    #pragma unroll
    for (int i = 0; i < 4; i++) {
      int c = i * 256 + t;
      int row = c >> 3, ko = (c & 7) * 8;
      uint4 av = make_uint4(0u, 0u, 0u, 0u);
      int gr = row0 + row;
      if (gr < NN) {
        float4 f0 = *(const float4*)&A32[(size_t)gr * 128 + kt + ko];
        float4 f1 = *(const float4*)&A32[(size_t)gr * 128 + kt + ko + 4];
        av = make_uint4(pk2(f0.x, f0.y), pk2(f0.z, f0.w), pk2(f1.x, f1.y), pk2(f1.z, f1.w));
      }
      *(uint4*)&As[row * 72 + ko] = av;
      uint4 bw = *(const uint4*)&BT[(size_t)(cb * 128 + row) * 128 + kt + ko];
      *(uint4*)&Bs[row * 72 + ko] = bw;
    }
    __syncthreads();
    #pragma unroll
    for (int kk = 0; kk < 64; kk += 32) {
      bf16x8 af[4], bfr[4];
      #pragma unroll
      for (int mf = 0; mf < 4; mf++)
        af[mf] = *(const bf16x8*)&As[(wm + mf * 16 + (l & 15)) * 72 + (l >> 4) * 8 + kk];
      #pragma unroll
      for (int nf = 0; nf < 4; nf++)
        bfr[nf] = *(const bf16x8*)&Bs[(wn + nf * 16 + (l & 15)) * 72 + (l >> 4) * 8 + kk];
      #pragma unroll
      for (int mf = 0; mf < 4; mf++)
        #pragma unroll
        for (int nf = 0; nf < 4; nf++)
          acc[mf][nf] = __builtin_amdgcn_mfma_f32_16x16x32_bf16(af[mf], bfr[nf], acc[mf][nf], 0, 0, 0);
    }
  }
}

__global__ __launch_bounds__(256) void k_gemm_o(
    const uint16_t* __restrict__ BT, const float* __restrict__ bo,
    const uint16_t* __restrict__ vp, float* __restrict__ dout) {
  __shared__ __align__(16) uint16_t As[128 * 72];
  __shared__ __align__(16) uint16_t Bs[128 * 72];
  float* xagg = dout;
  float* vecagg = dout + (size_t)NN * 128;
  int t = threadIdx.x;
  int l = t & 63;
  int row0 = blockIdx.y * 128;
  int wm = ((t >> 6) >> 1) * 64, wn = ((t >> 6) & 1) * 64;
  f32x4 acc0[4][4] = {}, acc1[4][4] = {}, acc2[4][4] = {};
  o_pass(xagg, BT, row0, 0, t, l, wm, wn, As, Bs, acc0);
  o_pass(xagg, BT, row0, 1, t, l, wm, wn, As, Bs, acc1);
  o_pass(xagg, BT, row0, 2, t, l, wm, wn, As, Bs, acc2);
  int d = l & 15;
  #pragma unroll
  for (int mf = 0; mf < 4; mf++) {
    #pragma unroll
    for (int r = 0; r < 4; r++) {
      int grow = row0 + wm + mf * 16 + (l >> 4) * 4 + r;
      if (grow >= NN) continue;
      const uint16_t* vpn = vp + (size_t)grow * 1152;
      #pragma unroll
      for (int nf = 0; nf < 4; nf++) {
        int col = wn + nf * 16 + d;
        float o1 = acc0[mf][nf][r] + bo[col];
        float o2 = acc1[mf][nf][r] + bo[128 + col];
        float o3 = acc2[mf][nf][r] + bo[256 + col];
        float vd = 0.f;
        #pragma unroll
        for (int c = 0; c < 3; c++)
          vd += bf2f(vpn[c * 384 + col]) * bf2f(vpn[c * 384 + 128 + col]);
        xagg[(size_t)grow * 128 + col] = vd * o2 + o3;
        #pragma unroll
        for (int c = 0; c < 3; c++) {
          size_t vi = ((size_t)grow * 3 + c) * 128 + col;
          vecagg[vi] = bf2f(vpn[c * 384 + 256 + col]) * o1 + vecagg[vi];
        }
      }
    }
  }
}

// ---------------- FULLY FUSED edge phase (R15-proven: 32-edge halves, combo 12B walk) ----------------
#define MTS 516   // walk-tile row stride (shorts): slots 0=xm 1=m1 2=m2, 3 pad

__device__ __forceinline__ void mfma32(const uint16_t* As, int r0,
                                       const uint16_t* __restrict__ BT2, int cb,
                                       int wn, int l, f32x4 acc[2][2]) {
  #pragma unroll
  for (int kk = 0; kk < 2; kk++) {
    bf16x8 af[2];
    #pragma unroll
    for (int mf = 0; mf < 2; mf++)
      af[mf] = *(const bf16x8*)&As[(r0 + mf * 16 + (l & 15)) * 68 + (l >> 4) * 8 + kk * 32];
    #pragma unroll
    for (int nf = 0; nf < 2; nf++) {
      bf16x8 bv = *(const bf16x8*)&BT2[(size_t)(cb * 128 + wn + nf * 16 + (l & 15)) * 64 +
                                       (l >> 4) * 8 + kk * 32];
      #pragma unroll
      for (int mf = 0; mf < 2; mf++)
        acc[mf][nf] = __builtin_amdgcn_mfma_f32_16x16x32_bf16(af[mf], bv, acc[mf][nf], 0, 0, 0);
    }
  }
}

__device__ __forceinline__ void silu_slot(uint16_t* mt, const float bsv[2], int slot,
                                          int wn, int l, f32x4 acc[2][2]) {
  #pragma unroll
  for (int mf = 0; mf < 2; mf++)
    #pragma unroll
    for (int r = 0; r < 4; r++) {
      int row = mf * 16 + (l >> 4) * 4 + r;
      #pragma unroll
      for (int nf = 0; nf < 2; nf++) {
        int c = wn + nf * 16 + (l & 15);
        mt[row * MTS + c * 4 + slot] = f2bf(siluf(acc[mf][nf][r] + bsv[nf]));
      }
    }
}

__device__ __forceinline__ void silu_dk(uint16_t* mtd, const float bsv[2],
                                        int wn, int l, f32x4 acc[2][2]) {
  #pragma unroll
  for (int mf = 0; mf < 2; mf++)
    #pragma unroll
    for (int r = 0; r < 4; r++) {
      int row = mf * 16 + (l >> 4) * 4 + r;
      #pragma unroll
      for (int nf = 0; nf < 2; nf++) {
        int c = wn + nf * 16 + (l & 15);
        mtd[row * 140 + c] = f2bf(siluf(acc[mf][nf][r] + bsv[nf]));
      }
    }
}

__global__ __launch_bounds__(256) void k_edge_all(
    const float* __restrict__ ea, const int* __restrict__ perm,
    const int* __restrict__ sndp, const int* __restrict__ rcvp,
    const int* __restrict__ off, const float4* __restrict__ edata,
    const uint16_t* __restrict__ WT2, const float* __restrict__ Bd2,
    const uint16_t* __restrict__ qk_b, const uint16_t* __restrict__ combo,
    float* __restrict__ xagg, float* __restrict__ vecagg) {
  __shared__ __align__(16) uint16_t As[64 * 68];     // 8.7 KB
  __shared__ __align__(16) uint16_t mt[32 * MTS];    // 33 KB (xm,m1,m2 slots)
  __shared__ __align__(16) uint16_t mtd[32 * 140];   // 8.96 KB (dk)
  __shared__ float attn_l[32 * 8];                   // 1 KB
  __shared__ int sndl[64], rcvl[64], lo_g[64], hi_g[64];
  __shared__ float4 ed4[64];

  int e0 = blockIdx.x * 64;
  int t = threadIdx.x, l = t & 63, wn = (t >> 6) * 32;

  // ---- meta + A stage (in-kernel gather, f32 -> bf16) + bias regs ----
  if (t < 64) {
    int e = e0 + t;
    int r = rcvp[e];
    sndl[t] = sndp[e]; rcvl[t] = r;
    lo_g[t] = off[r]; hi_g[t] = off[r + 1];
    ed4[t] = edata[e];
  }
  {
    int row = t >> 2, qo = (t & 3) * 16;
    int pe = perm[e0 + row];
    const float* src = ea + (size_t)pe * 64 + qo;
    float4 f0 = *(const float4*)src;
    float4 f1 = *(const float4*)(src + 4);
    float4 f2 = *(const float4*)(src + 8);
    float4 f3 = *(const float4*)(src + 12);
    uint4 o0, o1;
    o0.x = pk2(f0.x, f0.y); o0.y = pk2(f0.z, f0.w);
    o0.z = pk2(f1.x, f1.y); o0.w = pk2(f1.z, f1.w);
    o1.x = pk2(f2.x, f2.y); o1.y = pk2(f2.z, f2.w);
    o1.z = pk2(f3.x, f3.y); o1.w = pk2(f3.z, f3.w);
    *(uint4*)&As[row * 68 + qo] = o0;
    *(uint4*)&As[row * 68 + qo + 8] = o1;
  }
  float bs[4][2];
  #pragma unroll
  for (int cb = 0; cb < 4; cb++) {
    bs[cb][0] = Bd2[cb * 128 + wn + (l & 15)];
    bs[cb][1] = Bd2[cb * 128 + wn + 16 + (l & 15)];
  }
  __syncthreads();

  #pragma unroll
  for (int half = 0; half < 2; half++) {
    int r0 = half * 32;
    // ---- P1: cb0 dk -> mtd ----
    { f32x4 acc[2][2] = {}; mfma32(As, r0, WT2, 0, wn, l, acc); silu_dk(mtd, bs[0], wn, l, acc); }
    __syncthreads();
    // ---- P2: q/k loads early, cb1-3 MFMA hide them, then attn dot ----
    {
      int el = t >> 3, h = t & 7;
      int ge = r0 + el;
      int rn = rcvl[ge], sn = sndl[ge];
      const uint16_t* qb_ = qk_b + (size_t)rn * 256 + h * 16;
      const uint16_t* kb_ = qk_b + (size_t)sn * 256 + 128 + h * 16;
      uint4 q0 = *(const uint4*)qb_;
      uint4 q1 = *(const uint4*)(qb_ + 8);
      uint4 k0 = *(const uint4*)kb_;
      uint4 k1 = *(const uint4*)(kb_ + 8);
      { f32x4 acc[2][2] = {}; mfma32(As, r0, WT2, 1, wn, l, acc); silu_slot(mt, bs[1], 0, wn, l, acc); }
      { f32x4 acc[2][2] = {}; mfma32(As, r0, WT2, 2, wn, l, acc); silu_slot(mt, bs[2], 1, wn, l, acc); }
      { f32x4 acc[2][2] = {}; mfma32(As, r0, WT2, 3, wn, l, acc); silu_slot(mt, bs[3], 2, wn, l, acc); }
      const uint32_t* dp = (const uint32_t*)&mtd[el * 140 + h * 16];
      uint32_t qa[8] = {q0.x, q0.y, q0.z, q0.w, q1.x, q1.y, q1.z, q1.w};
      uint32_t ka[8] = {k0.x, k0.y, k0.z, k0.w, k1.x, k1.y, k1.z, k1.w};
      float dot = 0.f;
      #pragma unroll
      for (int j = 0; j < 8; j++) dot += prod2(qa[j], ka[j], dp[j]);
      attn_l[el * 8 + h] = siluf(dot) * ed4[ge].w;
    }
    __syncthreads();
    // ---- P3: merged walk; 12B combo gather per (edge,col) ----
    {
      int col = t & 127, sub = t >> 7;
      int i0 = r0 + sub * 16, i1 = i0 + 16;
      int ha = col >> 4;
      float accx = 0.f, a0 = 0.f, a1 = 0.f, a2 = 0.f;
      #pragma unroll 8
      for (int i = i0; i < i1; i++) {
        int li = i - r0;
        int n = rcvl[i], s = sndl[i];
        const uint16_t* cp = &combo[(size_t)s * 768 + col * 6];
        uint32_t u0 = *(const uint32_t*)cp;        // v0|v1
        uint32_t u1 = *(const uint32_t*)(cp + 2);  // v2|w0
        uint32_t u2 = *(const uint32_t*)(cp + 4);  // w1|w2
        uint2 mr = *(const uint2*)&mt[li * MTS + col * 4];
        float a = attn_l[li * 8 + ha];
        float xmv = bf2f(mr.x & 0xffffu), m1v = bf2f(mr.x >> 16), m2v = bf2f(mr.y & 0xffffu);
        accx += bf2f(u0 & 0xffffu) * xmv * a;
        float mm1 = bf2f(u0 >> 16) * m1v;
        float mm2 = bf2f(u1 & 0xffffu) * m2v;
        float4 ev = ed4[i];
        a0 += bf2f(u1 >> 16)     * mm1 + ev.x * mm2;
        a1 += bf2f(u2 & 0xffffu) * mm1 + ev.y * mm2;
        a2 += bf2f(u2 >> 16)     * mm1 + ev.z * mm2;
        if (i == i1 - 1 || rcvl[i + 1] != n) {
          bool cont = (lo_g[i] >= e0 + i0) && (hi_g[i] <= e0 + i1);
          float* dx_ = &xagg[(size_t)n * 128 + col];
          float* d0 = &vecagg[((size_t)n * 3 + 0) * 128 + col];
          float* d1 = &vecagg[((size_t)n * 3 + 1) * 128 + col];
          float* d2 = &vecagg[((size_t)n * 3 + 2) * 128 + col];
          if (cont) { *dx_ = accx; *d0 = a0; *d1 = a1; *d2 = a2; }
          else { atomicAdd(dx_, accx); atomicAdd(d0, a0); atomicAdd(d1, a1); atomicAdd(d2, a2); }
          accx = a0 = a1 = a2 = 0.f;
        }
      }
    }
    __syncthreads();
  }
}

static inline int cdiv_i(long long a, long long b) { return (int)((a + b - 1) / b); }

extern "C" void kernel_launch(void* const* d_in, const int* in_sizes, int n_in,
                              void* d_out, int out_size, void* d_ws, size_t ws_size,
                              hipStream_t stream) {
  const float* x    = (const float*)d_in[0];
  const float* vec  = (const float*)d_in[1];
  const float* ew   = (const float*)d_in[2];
  const float* ea   = (const float*)d_in[3];
  const float* evec = (const float*)d_in[4];
  const int*   snd  = (const int*)d_in[5];
  const int*   rcv  = (const int*)d_in[6];
  const float* ln_s = (const float*)d_in[7];
  const float* ln_b = (const float*)d_in[8];
  const float* Wq = (const float*)d_in[9];   const float* bq = (const float*)d_in[10];
  const float* Wk = (const float*)d_in[11];  const float* bk = (const float*)d_in[12];
  const float* Wv = (const float*)d_in[13];  const float* bv = (const float*)d_in[14];
  const float* Wvec = (const float*)d_in[15];
  const float* Wdk = (const float*)d_in[16]; const float* bdk = (const float*)d_in[17];
  const float* Wdv = (const float*)d_in[18]; const float* bdv = (const float*)d_in[19];
  const float* Wo = (const float*)d_in[20];  const float* bo = (const float*)d_in[21];
  const float* qln_s = (const float*)d_in[22]; const float* qln_b = (const float*)d_in[23];
  const float* kln_s = (const float*)d_in[24]; const float* kln_b = (const float*)d_in[25];
  (void)in_sizes; (void)n_in; (void)out_size; (void)ws_size;

  uint8_t* p = (uint8_t*)d_ws;
  auto alloc = [&](size_t bytes) -> uint8_t* {
    uint8_t* r = p; p += (bytes + 255) & ~(size_t)255; return r;
  };
  uint16_t* WTqkv = (uint16_t*)alloc(768 * 128 * 2);
  float*    Bqkv  = (float*)alloc(768 * 4);
  uint16_t* WTvec = (uint16_t*)alloc(384 * 128 * 2);
  uint16_t* WTdkv = (uint16_t*)alloc(512 * 64 * 2);
  float*    Bdkv  = (float*)alloc(512 * 4);
  uint16_t* WTo   = (uint16_t*)alloc(384 * 128 * 2);
  int*      deg   = (int*)alloc(NN * 4);
  int*      off   = (int*)alloc((NN + 1) * 4);
  int*      cur   = (int*)alloc(NN * 4);
  int*      bsum  = (int*)alloc(256 * 4);
  int*      perm  = (int*)alloc((size_t)NE * 4);
  int*      sndp  = (int*)alloc((size_t)NE * 4);
  int*      rcvp  = (int*)alloc((size_t)NE * 4);
  float4*   edata = (float4*)alloc((size_t)NE * 16);
  uint16_t* xn_b  = (uint16_t*)alloc((size_t)NN * 128 * 2);
  uint16_t* qk_raw = (uint16_t*)alloc((size_t)NN * 256 * 2);
  uint16_t* qk_b  = (uint16_t*)alloc((size_t)NN * 256 * 2);
  uint16_t* combo = (uint16_t*)alloc((size_t)NN * 768 * 2);
  uint16_t* vp    = (uint16_t*)alloc((size_t)NN * 3 * 384 * 2);

  float* xagg   = (float*)d_out;
  float* vecagg = (float*)d_out + (size_t)NN * 128;

  // ---- weights prep + deg zero (1 launch) ----
  k_prep<<<cdiv_i(98304 + 49152 + 32768 + 49152 + 1280 + NN, 256), 256, 0, stream>>>(
      Wq, Wk, Wv, Wvec, Wdk, Wdv, Wo, bq, bk, bv, bdk, bdv,
      WTqkv, WTvec, WTdkv, WTo, Bqkv, Bdkv, deg);

  // ---- edge sort by receiver ----
  int NSB = cdiv_i(NN, 256);
  k_hist<<<cdiv_i(NE, 256), 256, 0, stream>>>(rcv, deg);
  k_scan1<<<NSB, 256, 0, stream>>>(deg, bsum);
  k_scan2<<<1, 64, 0, stream>>>(bsum, NSB, off);
  k_scan3<<<NSB, 256, 0, stream>>>(deg, bsum, off, cur);
  k_scatter<<<cdiv_i(NE, 256), 256, 0, stream>>>(rcv, cur, perm);
  k_permute<<<cdiv_i(NE, 256), 256, 0, stream>>>(perm, snd, rcv, ew, evec, sndp, rcvp, edata);

  // ---- node pre (LN + combo w-slots + zero d_out) ----
  k_node_pre<<<25000, 256, 0, stream>>>(x, ln_s, ln_b, vec, xn_b, combo, (float4*)d_out);

  // qkv GEMM: q/k plain -> qk_raw; v -> combo slots 0-2
  { dim3 g(6, cdiv_i(NN, 128));
    k_gemm_qkv2<<<g, 256, 0, stream>>>(xn_b, WTqkv, Bqkv, qk_raw, combo); }
  k_headln<<<cdiv_i((long long)NN * 16, 256), 256, 0, stream>>>(qk_raw, qln_s, qln_b,
                                                               kln_s, kln_b, qk_b);

  // vp = vec @ Wvec (f32 A staged to bf16; bf16 out)
  { dim3 g(384 / 128, cdiv_i((long long)NN * 3, 128));
    k_gemm<128, true, false, true><<<g, 256, 0, stream>>>(vec, WTvec, nullptr, vp, NN * 3, 384); }

  // ---- fully fused edge phase (in-kernel ea gather; R15-proven) ----
  k_edge_all<<<NE / 64, 256, 0, stream>>>(ea, perm, sndp, rcvp, off, edata, WTdkv, Bdkv,
                                          qk_b, combo, xagg, vecagg);

  // ---- o-GEMM with fused final epilogue (in-place on d_out) ----
  { dim3 g(1, cdiv_i(NN, 128));
    k_gemm_o<<<g, 256, 0, stream>>>(WTo, bo, vp, (float*)d_out); }
}